// Round 7
// baseline (1087.769 us; speedup 1.0000x reference)
//
#include <hip/hip_runtime.h>

#define NIN 64
#define NOUT 32
#define KK 9

typedef __attribute__((ext_vector_type(8))) short bf16x8;
typedef __attribute__((ext_vector_type(16))) float f32x16;
typedef __attribute__((ext_vector_type(8))) unsigned short u16x8;

// fp32 -> bf16 round-to-nearest-even
__device__ __forceinline__ unsigned short f2bf_rne(float f) {
    unsigned int u = __builtin_bit_cast(unsigned int, f);
    unsigned int r = (u + 0x7FFFu + ((u >> 16) & 1u)) >> 16;
    return (unsigned short)r;
}
__device__ __forceinline__ float bf2f(unsigned short h) {
    unsigned int u = ((unsigned int)h) << 16;
    return __builtin_bit_cast(float, u);
}

// ---------------------------------------------------------------------------
// Pre-pack weights into MFMA B-fragment layout, split bf16 hi/lo.
__global__ void mink_prep_w(const float* __restrict__ w,
                            unsigned short* __restrict__ wf) {
    int t = blockIdx.x * 256 + threadIdx.x;
    if (t >= KK * 4 * 64) return;
    int l = t & 63, ks = (t >> 6) & 3, k = t >> 8;
    int col = l & 31;
    int kb = ks * 16 + (l >> 5) * 4;
    #pragma unroll
    for (int j = 0; j < 8; ++j) {
        int c = kb + (j & 3) + 8 * (j >> 2);
        float v = w[(k * NIN + c) * NOUT + col];
        unsigned short hi = f2bf_rne(v);
        unsigned short lo = f2bf_rne(v - bf2f(hi));
        wf[(size_t)((k * 4 + ks) * 64 + l) * 8 + j] = hi;
        wf[(size_t)(KK * 4 * 64 * 8) + (size_t)((k * 4 + ks) * 64 + l) * 8 + j] = lo;
    }
}

// ---------------------------------------------------------------------------
// Generic int fill (value v) -- used for buf=0, inv=-1, repmin=INT_MAX.
__global__ void mink_fill(int4* __restrict__ p, long long n4, int v) {
    long long i = (long long)blockIdx.x * 256 + threadIdx.x;
    long long stride = (long long)gridDim.x * 256;
    int4 val = {v, v, v, v};
    for (; i < n4; i += stride) p[i] = val;
}

// ---------------------------------------------------------------------------
// Step 1: representative site per cell = min site id sharing the center row.
__global__ void mink_rep(const int* __restrict__ oidx, int* __restrict__ repmin,
                         int n) {
    int i = blockIdx.x * 256 + threadIdx.x;
    if (i < n) atomicMin(&repmin[oidx[(size_t)i * KK + 4]], i);
}

// ---------------------------------------------------------------------------
// Step 2: every site adds its features into buf[rep] (fp32). Only ~0.5M
// line-RMW -> ~30us at the measured 18.5 G lines/s atomic cap.
__global__ void mink_accum(const float* __restrict__ feats,
                           const int* __restrict__ oidx,
                           const int* __restrict__ repmin,
                           float* __restrict__ buf, int n) {
    int i = blockIdx.x * 256 + threadIdx.x;
    if (i >= n) return;
    int rep = repmin[oidx[(size_t)i * KK + 4]];
    const float4* src = (const float4*)(feats + (size_t)i * NIN);
    float* dst = buf + (size_t)rep * NIN;
    #pragma unroll
    for (int j = 0; j < NIN / 4; ++j) {
        float4 v = src[j];
        unsafeAtomicAdd(dst + j * 4 + 0, v.x);
        unsafeAtomicAdd(dst + j * 4 + 1, v.y);
        unsafeAtomicAdd(dst + j * 4 + 2, v.z);
        unsafeAtomicAdd(dst + j * 4 + 3, v.w);
    }
}

// ---------------------------------------------------------------------------
// Step 3: representative sites convert their summed row to split-bf16
// A-fragment layout IN PLACE (read 64 floats to regs, then overwrite).
// Layout per site (256 B): [half][term hi/lo][ks] x 16 B, elem j of the 16 B
// block = chan ks*16 + half*4 + (j&3) + 8*(j>>2), matching the round-4 A-frag.
__global__ void mink_pack(const int* __restrict__ oidx,
                          const int* __restrict__ repmin,
                          float* __restrict__ buf, int n) {
    int i = blockIdx.x * 256 + threadIdx.x;
    if (i >= n) return;
    if (repmin[oidx[(size_t)i * KK + 4]] != i) return;

    float x[NIN];
    float4* p4 = (float4*)(buf + (size_t)i * NIN);
    #pragma unroll
    for (int j = 0; j < NIN / 4; ++j) {
        float4 v = p4[j];
        x[j * 4 + 0] = v.x; x[j * 4 + 1] = v.y;
        x[j * 4 + 2] = v.z; x[j * 4 + 3] = v.w;
    }
    #pragma unroll
    for (int half = 0; half < 2; ++half) {
        #pragma unroll
        for (int ks = 0; ks < 4; ++ks) {
            u16x8 hi, lo;
            #pragma unroll
            for (int j = 0; j < 8; ++j) {
                int c = ks * 16 + half * 4 + (j & 3) + 8 * (j >> 2);
                unsigned short h = f2bf_rne(x[c]);
                hi[j] = h;
                lo[j] = f2bf_rne(x[c] - bf2f(h));
            }
            p4[half * 8 + 0 + ks] = __builtin_bit_cast(float4, hi);
            p4[half * 8 + 4 + ks] = __builtin_bit_cast(float4, lo);
        }
    }
}

// ---------------------------------------------------------------------------
// Step 4: inverse maps. Only representatives write; per k the map is
// injective over cells -> plain stores, no races.
__global__ void mink_inv(const int* __restrict__ oidx,
                         const int* __restrict__ repmin,
                         int* __restrict__ inv, int n, int num_out) {
    int i = blockIdx.x * 256 + threadIdx.x;
    if (i >= n) return;
    if (repmin[oidx[(size_t)i * KK + 4]] != i) return;
    #pragma unroll
    for (int k = 0; k < KK; ++k)
        inv[(size_t)k * num_out + oidx[(size_t)i * KK + k]] = i;
}

// ---------------------------------------------------------------------------
// Step 5: gather kernel. One wave per 32 output rows; 9 k-phases gathering
// pre-packed split-bf16 A-frags; 12 MFMA per phase; single coalesced store
// per row with fused bias+ReLU. No atomics, no LDS, no syncthreads.
__global__ __launch_bounds__(256) void mink_gather_inv(
    const float* __restrict__ buf,          // packed A-frags per rep site
    const unsigned short* __restrict__ wf,  // packed B-frags (hi, lo)
    const int* __restrict__ inv,            // [9][num_out]
    const float* __restrict__ bias,         // [32]
    float* __restrict__ out,                // [num_out, 32]
    int num_out) {
    int wid  = (blockIdx.x * 256 + threadIdx.x) >> 6;
    int lane = threadIdx.x & 63;
    int r0   = wid * 32;
    if (r0 >= num_out) return;
    int half = lane >> 5;
    int col  = lane & 31;
    int r    = r0 + col;

    const bf16x8* wfh = (const bf16x8*)wf;
    const bf16x8* wfl = wfh + KK * 4 * 64;

    f32x16 acc = {0,0,0,0,0,0,0,0,0,0,0,0,0,0,0,0};

    #pragma unroll
    for (int k = 0; k < KK; ++k) {
        int iv = (r < num_out) ? inv[(size_t)k * num_out + r] : -1;

        bf16x8 ah[4], al[4];
        #pragma unroll
        for (int ks = 0; ks < 4; ++ks) {
            ah[ks] = (bf16x8){0,0,0,0,0,0,0,0};
            al[ks] = (bf16x8){0,0,0,0,0,0,0,0};
        }
        if (iv >= 0) {
            const bf16x8* base =
                (const bf16x8*)(buf + (size_t)iv * NIN) + half * 8;
            #pragma unroll
            for (int ks = 0; ks < 4; ++ks) {
                ah[ks] = base[ks];
                al[ks] = base[4 + ks];
            }
        }
        #pragma unroll
        for (int ks = 0; ks < 4; ++ks) {
            bf16x8 bh = wfh[(k * 4 + ks) * 64 + lane];
            bf16x8 bl = wfl[(k * 4 + ks) * 64 + lane];
            acc = __builtin_amdgcn_mfma_f32_32x32x16_bf16(ah[ks], bh, acc, 0, 0, 0);
            acc = __builtin_amdgcn_mfma_f32_32x32x16_bf16(ah[ks], bl, acc, 0, 0, 0);
            acc = __builtin_amdgcn_mfma_f32_32x32x16_bf16(al[ks], bh, acc, 0, 0, 0);
        }
    }

    float bb = bias[col];
    #pragma unroll
    for (int rr = 0; rr < 16; ++rr) {
        int m = (rr & 3) + 8 * (rr >> 2) + 4 * half;
        int orow = r0 + m;
        if (orow < num_out)
            out[(size_t)orow * NOUT + col] = fmaxf(acc[rr] + bb, 0.0f);
    }
}

// ---------------------------------------------------------------------------
// Fallback path (round-4 atomic scatter) if d_ws is too small.
__global__ void mink_init_bias(float4* __restrict__ out,
                               const float4* __restrict__ bias, int n4) {
    int i = blockIdx.x * blockDim.x + threadIdx.x;
    if (i < n4) out[i] = bias[i & 7];
}

__global__ __launch_bounds__(256) void mink_scatter_mfma(
    const float* __restrict__ feats,
    const unsigned short* __restrict__ wf,
    const int* __restrict__ out_idx,
    float* __restrict__ out,
    int ntiles) {
    int wid  = (blockIdx.x * 256 + threadIdx.x) >> 6;
    int lane = threadIdx.x & 63;
    if (wid >= ntiles) return;
    int n0   = wid * 32;
    int half = lane >> 5;
    int col  = lane & 31;

    const float* xrow = feats + (size_t)(n0 + col) * NIN;
    int kbase = half * 4;
    bf16x8 ahi[4], alo[4];
    #pragma unroll
    for (int ks = 0; ks < 4; ++ks) {
        float4 v0 = *(const float4*)(xrow + ks * 16 + kbase);
        float4 v1 = *(const float4*)(xrow + ks * 16 + kbase + 8);
        float xs[8] = {v0.x, v0.y, v0.z, v0.w, v1.x, v1.y, v1.z, v1.w};
        #pragma unroll
        for (int j = 0; j < 8; ++j) {
            unsigned short h = f2bf_rne(xs[j]);
            ahi[ks][j] = (short)h;
            alo[ks][j] = (short)f2bf_rne(xs[j] - bf2f(h));
        }
    }
    const bf16x8* wfh = (const bf16x8*)wf;
    const bf16x8* wfl = wfh + KK * 4 * 64;
    #pragma unroll 1
    for (int k = 0; k < KK; ++k) {
        f32x16 acc = {0,0,0,0,0,0,0,0,0,0,0,0,0,0,0,0};
        #pragma unroll
        for (int ks = 0; ks < 4; ++ks) {
            bf16x8 bh = wfh[(k * 4 + ks) * 64 + lane];
            bf16x8 bl = wfl[(k * 4 + ks) * 64 + lane];
            acc = __builtin_amdgcn_mfma_f32_32x32x16_bf16(ahi[ks], bh, acc, 0, 0, 0);
            acc = __builtin_amdgcn_mfma_f32_32x32x16_bf16(ahi[ks], bl, acc, 0, 0, 0);
            acc = __builtin_amdgcn_mfma_f32_32x32x16_bf16(alo[ks], bh, acc, 0, 0, 0);
        }
        #pragma unroll
        for (int rr = 0; rr < 16; ++rr) {
            int site = (rr & 3) + 8 * (rr >> 2) + 4 * half;
            int row = out_idx[(size_t)(n0 + site) * KK + k];
            unsafeAtomicAdd(out + (size_t)row * NOUT + col, acc[rr]);
        }
    }
}

__global__ void mink_relu(float4* __restrict__ out, int n4) {
    int i = blockIdx.x * blockDim.x + threadIdx.x;
    if (i < n4) {
        float4 v = out[i];
        v.x = fmaxf(v.x, 0.0f);
        v.y = fmaxf(v.y, 0.0f);
        v.z = fmaxf(v.z, 0.0f);
        v.w = fmaxf(v.w, 0.0f);
        out[i] = v;
    }
}

extern "C" void kernel_launch(void* const* d_in, const int* in_sizes, int n_in,
                              void* d_out, int out_size, void* d_ws, size_t ws_size,
                              hipStream_t stream) {
    const float* feats  = (const float*)d_in[0];  // [N, 64] f32
    const float* weight = (const float*)d_in[1];  // [9, 64, 32] f32
    const float* bias   = (const float*)d_in[2];  // [32] f32
    const int*   oidx   = (const int*)d_in[3];    // [N, 9] i32
    float* out = (float*)d_out;                   // [num_out, 32] f32

    int n       = in_sizes[0] / NIN;              // 262144
    int n4      = out_size / 4;
    int num_out = out_size / NOUT;

    // d_ws layout: wf | repmin[num_out] | inv[9*num_out] | buf[n*64 f32]
    unsigned short* wf = (unsigned short*)d_ws;
    size_t off = 73728;
    int* repmin = (int*)((char*)d_ws + off);  off += (size_t)num_out * 4;
    off = (off + 255) & ~(size_t)255;
    int* inv    = (int*)((char*)d_ws + off);  off += (size_t)KK * num_out * 4;
    off = (off + 255) & ~(size_t)255;
    float* buf  = (float*)((char*)d_ws + off); off += (size_t)n * NIN * 4;

    mink_prep_w<<<(KK * 4 * 64 + 255) / 256, 256, 0, stream>>>(weight, wf);

    if (off <= ws_size) {
        // ---- inverse-map gather path (no output atomics)
        long long buf4 = (long long)n * NIN / 4;
        long long inv4 = ((long long)KK * num_out + 3) / 4;
        long long rep4 = ((long long)num_out + 3) / 4;
        mink_fill<<<2048, 256, 0, stream>>>((int4*)buf, buf4, 0);
        mink_fill<<<1024, 256, 0, stream>>>((int4*)inv, inv4, -1);
        mink_fill<<<256, 256, 0, stream>>>((int4*)repmin, rep4, 0x7FFFFFFF);
        mink_rep<<<(n + 255) / 256, 256, 0, stream>>>(oidx, repmin, n);
        mink_accum<<<(n + 255) / 256, 256, 0, stream>>>(feats, oidx, repmin, buf, n);
        mink_pack<<<(n + 255) / 256, 256, 0, stream>>>(oidx, repmin, buf, n);
        mink_inv<<<(n + 255) / 256, 256, 0, stream>>>(oidx, repmin, inv, n, num_out);

        int nwid = (num_out + 31) / 32;
        mink_gather_inv<<<(nwid + 3) / 4, 256, 0, stream>>>(
            buf, wf, inv, bias, out, num_out);
    } else {
        // ---- fallback: round-4 atomic scatter
        mink_init_bias<<<(n4 + 255) / 256, 256, 0, stream>>>(
            (float4*)out, (const float4*)bias, n4);
        int ntiles = n / 32;
        mink_scatter_mfma<<<ntiles * 64 / 256, 256, 0, stream>>>(
            feats, wf, oidx, out, ntiles);
        mink_relu<<<(n4 + 255) / 256, 256, 0, stream>>>((float4*)out, n4);
    }
}

// Round 8
// 295.275 us; speedup vs baseline: 3.6839x; 3.6839x over previous
//
#include <hip/hip_runtime.h>

#define NIN 64
#define NOUT 32
#define KK 9

typedef __attribute__((ext_vector_type(8))) short bf16x8;
typedef __attribute__((ext_vector_type(16))) float f32x16;
typedef __attribute__((ext_vector_type(8))) unsigned short u16x8;

// fp32 -> bf16 round-to-nearest-even
__device__ __forceinline__ unsigned short f2bf_rne(float f) {
    unsigned int u = __builtin_bit_cast(unsigned int, f);
    unsigned int r = (u + 0x7FFFu + ((u >> 16) & 1u)) >> 16;
    return (unsigned short)r;
}
__device__ __forceinline__ float bf2f(unsigned short h) {
    unsigned int u = ((unsigned int)h) << 16;
    return __builtin_bit_cast(float, u);
}

// ---------------------------------------------------------------------------
// Pre-pack weights into MFMA B-fragment layout, split bf16 hi/lo.
__global__ void mink_prep_w(const float* __restrict__ w,
                            unsigned short* __restrict__ wf) {
    int t = blockIdx.x * 256 + threadIdx.x;
    if (t >= KK * 4 * 64) return;
    int l = t & 63, ks = (t >> 6) & 3, k = t >> 8;
    int col = l & 31;
    int kb = ks * 16 + (l >> 5) * 4;
    #pragma unroll
    for (int j = 0; j < 8; ++j) {
        int c = kb + (j & 3) + 8 * (j >> 2);
        float v = w[(k * NIN + c) * NOUT + col];
        unsigned short hi = f2bf_rne(v);
        unsigned short lo = f2bf_rne(v - bf2f(hi));
        wf[(size_t)((k * 4 + ks) * 64 + l) * 8 + j] = hi;
        wf[(size_t)(KK * 4 * 64 * 8) + (size_t)((k * 4 + ks) * 64 + l) * 8 + j] = lo;
    }
}

// ---------------------------------------------------------------------------
// Generic int fill.
__global__ void mink_fill(int4* __restrict__ p, long long n4, int v) {
    long long i = (long long)blockIdx.x * 256 + threadIdx.x;
    long long stride = (long long)gridDim.x * 256;
    int4 val = {v, v, v, v};
    for (; i < n4; i += stride) p[i] = val;
}

// ---------------------------------------------------------------------------
// Step 1: representative site per cell = min site id sharing the center row.
// (center row is unique per input coordinate; duplicates share all 9 rows)
__global__ void mink_rep(const int* __restrict__ oidx, int* __restrict__ repmin,
                         int n) {
    int i = blockIdx.x * 256 + threadIdx.x;
    if (i < n) atomicMin(&repmin[oidx[(size_t)i * KK + 4]], i);
}

// ---------------------------------------------------------------------------
// Step 2a: rep sites copy their features into buf (plain coalesced stores;
// non-rep rows of buf are never read, so no zero-fill needed).
// thread = site*64 + chan; one wave == one site -> repmin read is broadcast.
__global__ void mink_copy_reps(const float* __restrict__ feats,
                               const int* __restrict__ oidx,
                               const int* __restrict__ repmin,
                               float* __restrict__ buf, int n) {
    int t = blockIdx.x * 256 + threadIdx.x;
    int site = t >> 6;
    if (site >= n) return;
    int rep = repmin[oidx[(size_t)site * KK + 4]];
    if (rep == site) buf[t] = feats[t];
}

// ---------------------------------------------------------------------------
// Step 2b: duplicate sites (rep != site, ~37%) atomically add their features
// into buf[rep]. Wave's 64 lanes cover the 64 CONSECUTIVE channels of one
// site -> 4 line touches per site (vs 64 in round 7's per-thread layout).
__global__ void mink_dup_accum(const float* __restrict__ feats,
                               const int* __restrict__ oidx,
                               const int* __restrict__ repmin,
                               float* __restrict__ buf, int n) {
    int t = blockIdx.x * 256 + threadIdx.x;
    int site = t >> 6;
    if (site >= n) return;
    int c = t & 63;
    int rep = repmin[oidx[(size_t)site * KK + 4]];
    if (rep != site)
        unsafeAtomicAdd(buf + (size_t)rep * NIN + c, feats[t]);
}

// ---------------------------------------------------------------------------
// Step 3: rep sites convert their summed fp32 row to split-bf16 A-fragment
// layout IN PLACE. Layout per site (256 B): [half][hi/lo][ks] x 16 B; elem j
// of a block = chan ks*16 + half*4 + (j&3) + 8*(j>>2)  (matches B-frag K-map).
__global__ void mink_pack(const int* __restrict__ oidx,
                          const int* __restrict__ repmin,
                          float* __restrict__ buf, int n) {
    int i = blockIdx.x * 256 + threadIdx.x;
    if (i >= n) return;
    if (repmin[oidx[(size_t)i * KK + 4]] != i) return;

    float x[NIN];
    float4* p4 = (float4*)(buf + (size_t)i * NIN);
    #pragma unroll
    for (int j = 0; j < NIN / 4; ++j) {
        float4 v = p4[j];
        x[j * 4 + 0] = v.x; x[j * 4 + 1] = v.y;
        x[j * 4 + 2] = v.z; x[j * 4 + 3] = v.w;
    }
    #pragma unroll
    for (int half = 0; half < 2; ++half) {
        #pragma unroll
        for (int ks = 0; ks < 4; ++ks) {
            u16x8 hi, lo;
            #pragma unroll
            for (int j = 0; j < 8; ++j) {
                int c = ks * 16 + half * 4 + (j & 3) + 8 * (j >> 2);
                unsigned short h = f2bf_rne(x[c]);
                hi[j] = h;
                lo[j] = f2bf_rne(x[c] - bf2f(h));
            }
            p4[half * 8 + 0 + ks] = __builtin_bit_cast(float4, hi);
            p4[half * 8 + 4 + ks] = __builtin_bit_cast(float4, lo);
        }
    }
}

// ---------------------------------------------------------------------------
// Step 4: inverse maps (reps only; per k injective over cells -> plain stores).
__global__ void mink_inv(const int* __restrict__ oidx,
                         const int* __restrict__ repmin,
                         int* __restrict__ inv, int n, int num_out) {
    int i = blockIdx.x * 256 + threadIdx.x;
    if (i >= n) return;
    if (repmin[oidx[(size_t)i * KK + 4]] != i) return;
    #pragma unroll
    for (int k = 0; k < KK; ++k)
        inv[(size_t)k * num_out + oidx[(size_t)i * KK + k]] = i;
}

// ---------------------------------------------------------------------------
// Step 5: gather kernel. One wave per 32 output rows; 9 k-phases gathering
// pre-packed split-bf16 A-frags; 12 MFMA per phase; single coalesced store
// per row with fused bias+ReLU. No atomics, no LDS, no syncthreads.
__global__ __launch_bounds__(256) void mink_gather_inv(
    const float* __restrict__ buf,          // packed A-frags per rep site
    const unsigned short* __restrict__ wf,  // packed B-frags (hi, lo)
    const int* __restrict__ inv,            // [9][num_out]
    const float* __restrict__ bias,         // [32]
    float* __restrict__ out,                // [num_out, 32]
    int num_out) {
    int wid  = (blockIdx.x * 256 + threadIdx.x) >> 6;
    int lane = threadIdx.x & 63;
    int r0   = wid * 32;
    if (r0 >= num_out) return;
    int half = lane >> 5;
    int col  = lane & 31;
    int r    = r0 + col;

    const bf16x8* wfh = (const bf16x8*)wf;
    const bf16x8* wfl = wfh + KK * 4 * 64;

    f32x16 acc = {0,0,0,0,0,0,0,0,0,0,0,0,0,0,0,0};

    #pragma unroll
    for (int k = 0; k < KK; ++k) {
        int iv = (r < num_out) ? inv[(size_t)k * num_out + r] : -1;

        bf16x8 ah[4], al[4];
        #pragma unroll
        for (int ks = 0; ks < 4; ++ks) {
            ah[ks] = (bf16x8){0,0,0,0,0,0,0,0};
            al[ks] = (bf16x8){0,0,0,0,0,0,0,0};
        }
        if (iv >= 0) {
            const bf16x8* base =
                (const bf16x8*)(buf + (size_t)iv * NIN) + half * 8;
            #pragma unroll
            for (int ks = 0; ks < 4; ++ks) {
                ah[ks] = base[ks];
                al[ks] = base[4 + ks];
            }
        }
        #pragma unroll
        for (int ks = 0; ks < 4; ++ks) {
            bf16x8 bh = wfh[(k * 4 + ks) * 64 + lane];
            bf16x8 bl = wfl[(k * 4 + ks) * 64 + lane];
            acc = __builtin_amdgcn_mfma_f32_32x32x16_bf16(ah[ks], bh, acc, 0, 0, 0);
            acc = __builtin_amdgcn_mfma_f32_32x32x16_bf16(ah[ks], bl, acc, 0, 0, 0);
            acc = __builtin_amdgcn_mfma_f32_32x32x16_bf16(al[ks], bh, acc, 0, 0, 0);
        }
    }

    float bb = bias[col];
    #pragma unroll
    for (int rr = 0; rr < 16; ++rr) {
        int m = (rr & 3) + 8 * (rr >> 2) + 4 * half;
        int orow = r0 + m;
        if (orow < num_out)
            out[(size_t)orow * NOUT + col] = fmaxf(acc[rr] + bb, 0.0f);
    }
}

// ---------------------------------------------------------------------------
// Fallback path (round-4 atomic scatter) if d_ws is too small.
__global__ void mink_init_bias(float4* __restrict__ out,
                               const float4* __restrict__ bias, int n4) {
    int i = blockIdx.x * blockDim.x + threadIdx.x;
    if (i < n4) out[i] = bias[i & 7];
}

__global__ __launch_bounds__(256) void mink_scatter_mfma(
    const float* __restrict__ feats,
    const unsigned short* __restrict__ wf,
    const int* __restrict__ out_idx,
    float* __restrict__ out,
    int ntiles) {
    int wid  = (blockIdx.x * 256 + threadIdx.x) >> 6;
    int lane = threadIdx.x & 63;
    if (wid >= ntiles) return;
    int n0   = wid * 32;
    int half = lane >> 5;
    int col  = lane & 31;

    const float* xrow = feats + (size_t)(n0 + col) * NIN;
    int kbase = half * 4;
    bf16x8 ahi[4], alo[4];
    #pragma unroll
    for (int ks = 0; ks < 4; ++ks) {
        float4 v0 = *(const float4*)(xrow + ks * 16 + kbase);
        float4 v1 = *(const float4*)(xrow + ks * 16 + kbase + 8);
        float xs[8] = {v0.x, v0.y, v0.z, v0.w, v1.x, v1.y, v1.z, v1.w};
        #pragma unroll
        for (int j = 0; j < 8; ++j) {
            unsigned short h = f2bf_rne(xs[j]);
            ahi[ks][j] = (short)h;
            alo[ks][j] = (short)f2bf_rne(xs[j] - bf2f(h));
        }
    }
    const bf16x8* wfh = (const bf16x8*)wf;
    const bf16x8* wfl = wfh + KK * 4 * 64;
    #pragma unroll 1
    for (int k = 0; k < KK; ++k) {
        f32x16 acc = {0,0,0,0,0,0,0,0,0,0,0,0,0,0,0,0};
        #pragma unroll
        for (int ks = 0; ks < 4; ++ks) {
            bf16x8 bh = wfh[(k * 4 + ks) * 64 + lane];
            bf16x8 bl = wfl[(k * 4 + ks) * 64 + lane];
            acc = __builtin_amdgcn_mfma_f32_32x32x16_bf16(ahi[ks], bh, acc, 0, 0, 0);
            acc = __builtin_amdgcn_mfma_f32_32x32x16_bf16(ahi[ks], bl, acc, 0, 0, 0);
            acc = __builtin_amdgcn_mfma_f32_32x32x16_bf16(alo[ks], bh, acc, 0, 0, 0);
        }
        #pragma unroll
        for (int rr = 0; rr < 16; ++rr) {
            int site = (rr & 3) + 8 * (rr >> 2) + 4 * half;
            int row = out_idx[(size_t)(n0 + site) * KK + k];
            unsafeAtomicAdd(out + (size_t)row * NOUT + col, acc[rr]);
        }
    }
}

__global__ void mink_relu(float4* __restrict__ out, int n4) {
    int i = blockIdx.x * blockDim.x + threadIdx.x;
    if (i < n4) {
        float4 v = out[i];
        v.x = fmaxf(v.x, 0.0f);
        v.y = fmaxf(v.y, 0.0f);
        v.z = fmaxf(v.z, 0.0f);
        v.w = fmaxf(v.w, 0.0f);
        out[i] = v;
    }
}

extern "C" void kernel_launch(void* const* d_in, const int* in_sizes, int n_in,
                              void* d_out, int out_size, void* d_ws, size_t ws_size,
                              hipStream_t stream) {
    const float* feats  = (const float*)d_in[0];  // [N, 64] f32
    const float* weight = (const float*)d_in[1];  // [9, 64, 32] f32
    const float* bias   = (const float*)d_in[2];  // [32] f32
    const int*   oidx   = (const int*)d_in[3];    // [N, 9] i32
    float* out = (float*)d_out;                   // [num_out, 32] f32

    int n       = in_sizes[0] / NIN;              // 262144
    int n4      = out_size / 4;
    int num_out = out_size / NOUT;

    // d_ws layout: wf | repmin[num_out] | inv[9*num_out] | buf[n*64 f32]
    unsigned short* wf = (unsigned short*)d_ws;
    size_t off = 73728;
    int* repmin = (int*)((char*)d_ws + off);  off += (size_t)num_out * 4;
    off = (off + 255) & ~(size_t)255;
    int* inv    = (int*)((char*)d_ws + off);  off += (size_t)KK * num_out * 4;
    off = (off + 255) & ~(size_t)255;
    float* buf  = (float*)((char*)d_ws + off); off += (size_t)n * NIN * 4;

    mink_prep_w<<<(KK * 4 * 64 + 255) / 256, 256, 0, stream>>>(weight, wf);

    if (off <= ws_size) {
        // ---- inverse-map gather path (no output atomics)
        long long inv4 = ((long long)KK * num_out + 3) / 4;
        long long rep4 = ((long long)num_out + 3) / 4;
        mink_fill<<<1024, 256, 0, stream>>>((int4*)inv, inv4, -1);
        mink_fill<<<256, 256, 0, stream>>>((int4*)repmin, rep4, 0x7FFFFFFF);
        mink_rep<<<(n + 255) / 256, 256, 0, stream>>>(oidx, repmin, n);

        long long nthr = (long long)n * NIN;   // 16.8M, thread per (site,chan)
        mink_copy_reps<<<(int)(nthr / 256), 256, 0, stream>>>(
            feats, oidx, repmin, buf, n);
        mink_dup_accum<<<(int)(nthr / 256), 256, 0, stream>>>(
            feats, oidx, repmin, buf, n);

        mink_pack<<<(n + 255) / 256, 256, 0, stream>>>(oidx, repmin, buf, n);
        mink_inv<<<(n + 255) / 256, 256, 0, stream>>>(oidx, repmin, inv, n, num_out);

        int nwid = (num_out + 31) / 32;
        mink_gather_inv<<<(nwid + 3) / 4, 256, 0, stream>>>(
            buf, wf, inv, bias, out, num_out);
    } else {
        // ---- fallback: round-4 atomic scatter
        mink_init_bias<<<(n4 + 255) / 256, 256, 0, stream>>>(
            (float4*)out, (const float4*)bias, n4);
        int ntiles = n / 32;
        mink_scatter_mfma<<<ntiles * 64 / 256, 256, 0, stream>>>(
            feats, wf, oidx, out, ntiles);
        mink_relu<<<(n4 + 255) / 256, 256, 0, stream>>>((float4*)out, n4);
    }
}

// Round 9
// 285.706 us; speedup vs baseline: 3.8073x; 1.0335x over previous
//
#include <hip/hip_runtime.h>

#define NIN 64
#define NOUT 32
#define KK 9

typedef __attribute__((ext_vector_type(8))) short bf16x8;
typedef __attribute__((ext_vector_type(4))) float f32x4;
typedef __attribute__((ext_vector_type(16))) float f32x16;
typedef __attribute__((ext_vector_type(8))) unsigned short u16x8;

// fp32 -> bf16 round-to-nearest-even
__device__ __forceinline__ unsigned short f2bf_rne(float f) {
    unsigned int u = __builtin_bit_cast(unsigned int, f);
    unsigned int r = (u + 0x7FFFu + ((u >> 16) & 1u)) >> 16;
    return (unsigned short)r;
}
__device__ __forceinline__ float bf2f(unsigned short h) {
    unsigned int u = ((unsigned int)h) << 16;
    return __builtin_bit_cast(float, u);
}

// ---------------------------------------------------------------------------
// Weights for the 16x16x32 gather: split bf16 hi/lo ON W (x stays single
// bf16). frag id fid = ((k*2+kh)*2+ch)*2+term; elem j of lane l:
//   ch_idx = kh*32 + 16*(j>>2) + (l>>4)*4 + (j&3),  col = ch*16 + (l&15)
// (concatenated K-halves convention, verified by rounds 4-8 on 32x32x16)
__global__ void mink_prep_w16(const float* __restrict__ w,
                              unsigned short* __restrict__ wfB) {
    int t = blockIdx.x * 256 + threadIdx.x;
    if (t >= 72 * 64) return;
    int lane = t & 63, fid = t >> 6;
    int term = fid & 1, ch = (fid >> 1) & 1, kh = (fid >> 2) & 1, k = fid >> 3;
    int g = lane >> 4, col = ch * 16 + (lane & 15);
    #pragma unroll
    for (int j = 0; j < 8; ++j) {
        int ci = kh * 32 + 16 * (j >> 2) + g * 4 + (j & 3);
        float v = w[(k * NIN + ci) * NOUT + col];
        unsigned short hi = f2bf_rne(v);
        unsigned short val = term ? f2bf_rne(v - bf2f(hi)) : hi;
        wfB[(size_t)fid * 512 + lane * 8 + j] = val;
    }
}

// ---------------------------------------------------------------------------
// Generic int fill.
__global__ void mink_fill(int4* __restrict__ p, long long n4, int v) {
    long long i = (long long)blockIdx.x * 256 + threadIdx.x;
    long long stride = (long long)gridDim.x * 256;
    int4 val = {v, v, v, v};
    for (; i < n4; i += stride) p[i] = val;
}

// ---------------------------------------------------------------------------
// Step 1: representative site per cell = min site id sharing the center row.
__global__ void mink_rep(const int* __restrict__ oidx, int* __restrict__ repmin,
                         int n) {
    int i = blockIdx.x * 256 + threadIdx.x;
    if (i < n) atomicMin(&repmin[oidx[(size_t)i * KK + 4]], i);
}

// ---------------------------------------------------------------------------
// Step 2a: rep sites copy features into buf (plain stores, coalesced).
__global__ void mink_copy_reps(const float* __restrict__ feats,
                               const int* __restrict__ oidx,
                               const int* __restrict__ repmin,
                               float* __restrict__ buf, int n) {
    int t = blockIdx.x * 256 + threadIdx.x;
    int site = t >> 6;
    if (site >= n) return;
    int rep = repmin[oidx[(size_t)site * KK + 4]];
    if (rep == site) buf[t] = feats[t];
}

// ---------------------------------------------------------------------------
// Step 2b: duplicates add into buf[rep]; wave-coalesced channels -> 4 line
// touches per dup site. Wave-uniform predicate -> rep waves skip the load.
__global__ void mink_dup_accum(const float* __restrict__ feats,
                               const int* __restrict__ oidx,
                               const int* __restrict__ repmin,
                               float* __restrict__ buf, int n) {
    int t = blockIdx.x * 256 + threadIdx.x;
    int site = t >> 6;
    if (site >= n) return;
    int c = t & 63;
    int rep = repmin[oidx[(size_t)site * KK + 4]];
    if (rep != site)
        unsafeAtomicAdd(buf + (size_t)rep * NIN + c, feats[t]);
}

// ---------------------------------------------------------------------------
// Step 3: pack summed fp32 row -> single-bf16 A fragments, in place (128 B
// at the row start). chunk (kh,g) elem j: ch = kh*32 + 16*(j>>2) + g*4 + (j&3)
__global__ void mink_pack16(const int* __restrict__ oidx,
                            const int* __restrict__ repmin,
                            float* __restrict__ buf, int n) {
    int i = blockIdx.x * 256 + threadIdx.x;
    if (i >= n) return;
    if (repmin[oidx[(size_t)i * KK + 4]] != i) return;

    float x[NIN];
    float4* p4 = (float4*)(buf + (size_t)i * NIN);
    #pragma unroll
    for (int j = 0; j < NIN / 4; ++j) {
        float4 v = p4[j];
        x[j * 4 + 0] = v.x; x[j * 4 + 1] = v.y;
        x[j * 4 + 2] = v.z; x[j * 4 + 3] = v.w;
    }
    #pragma unroll
    for (int kh = 0; kh < 2; ++kh) {
        #pragma unroll
        for (int g = 0; g < 4; ++g) {
            u16x8 a;
            #pragma unroll
            for (int j = 0; j < 8; ++j) {
                int c = kh * 32 + 16 * (j >> 2) + g * 4 + (j & 3);
                a[j] = f2bf_rne(x[c]);
            }
            p4[kh * 4 + g] = __builtin_bit_cast(float4, a);
        }
    }
}

// ---------------------------------------------------------------------------
// Step 4a: center plane (k=4) of inv is exactly repmin (INT_MAX -> -1):
// streaming, no scatter.
__global__ void mink_inv4(const int* __restrict__ repmin, int* __restrict__ inv,
                          int num_out) {
    int r = blockIdx.x * 256 + threadIdx.x;
    if (r < num_out) {
        int v = repmin[r];
        inv[(size_t)4 * num_out + r] = (v == 0x7FFFFFFF) ? -1 : v;
    }
}

// Step 4b: remaining 8 planes (scattered stores, reps only).
__global__ void mink_inv8(const int* __restrict__ oidx,
                          const int* __restrict__ repmin,
                          int* __restrict__ inv, int n, int num_out) {
    int i = blockIdx.x * 256 + threadIdx.x;
    if (i >= n) return;
    if (repmin[oidx[(size_t)i * KK + 4]] != i) return;
    #pragma unroll
    for (int k = 0; k < KK; ++k) {
        if (k == 4) continue;
        inv[(size_t)k * num_out + oidx[(size_t)i * KK + k]] = i;
    }
}

// ---------------------------------------------------------------------------
// Step 5: 16x16x32 gather. One wave per 16 output rows; W (hi+lo) staged in
// LDS per 512-thread block; A-loads hit 16 lines/instr (4 lanes share a
// row's 64 B line). 8 MFMA per k. Single coalesced store, fused bias+ReLU.
__global__ __launch_bounds__(512) void mink_gather16(
    const float* __restrict__ buf,          // packed bf16 A rows (128 B used)
    const unsigned short* __restrict__ wfB, // 72 frags x 1 KB
    const int* __restrict__ inv,            // [9][num_out]
    const float* __restrict__ bias,         // [32]
    float* __restrict__ out,                // [num_out, 32]
    int num_out) {
    __shared__ unsigned short wlds[72 * 512];   // 72 KB
    {
        const int4* src = (const int4*)wfB;
        int4* dst = (int4*)wlds;
        for (int i = threadIdx.x; i < 72 * 512 / 8; i += 512) dst[i] = src[i];
    }
    __syncthreads();

    int wid  = (blockIdx.x * 512 + threadIdx.x) >> 6;
    int lane = threadIdx.x & 63;
    int r0   = wid * 16;
    if (r0 >= num_out) return;
    int g   = lane >> 4;
    int c16 = lane & 15;
    int r   = r0 + c16;
    bool rv = r < num_out;

    f32x4 acc0 = {0, 0, 0, 0}, acc1 = {0, 0, 0, 0};

    #pragma unroll
    for (int k = 0; k < KK; ++k) {
        int iv = rv ? inv[(size_t)k * num_out + r] : -1;
        bf16x8 a0 = {0,0,0,0,0,0,0,0}, a1 = {0,0,0,0,0,0,0,0};
        if (iv >= 0) {
            const bf16x8* ab = (const bf16x8*)(buf + (size_t)iv * NIN);
            a0 = ab[g];        // kh=0 chunk
            a1 = ab[4 + g];    // kh=1 chunk
        }
        #pragma unroll
        for (int kh = 0; kh < 2; ++kh) {
            bf16x8 a = kh ? a1 : a0;
            #pragma unroll
            for (int ch = 0; ch < 2; ++ch) {
                const unsigned short* p =
                    wlds + (size_t)(((k * 2 + kh) * 2 + ch) * 2) * 512 + lane * 8;
                bf16x8 bh = *(const bf16x8*)p;
                bf16x8 bl = *(const bf16x8*)(p + 512);
                f32x4& acc = ch ? acc1 : acc0;
                acc = __builtin_amdgcn_mfma_f32_16x16x32_bf16(a, bh, acc, 0, 0, 0);
                acc = __builtin_amdgcn_mfma_f32_16x16x32_bf16(a, bl, acc, 0, 0, 0);
            }
        }
    }

    // C/D: row = g*4 + reg, col = c16 (per m89-verified 16x16 layout)
    #pragma unroll
    for (int ch = 0; ch < 2; ++ch) {
        float bb = bias[ch * 16 + c16];
        f32x4 acc = ch ? acc1 : acc0;
        #pragma unroll
        for (int reg = 0; reg < 4; ++reg) {
            int orow = r0 + g * 4 + reg;
            if (orow < num_out)
                out[(size_t)orow * NOUT + ch * 16 + c16] =
                    fmaxf(acc[reg] + bb, 0.0f);
        }
    }
}

// ---------------------------------------------------------------------------
// Fallback path (round-4 atomic scatter) if d_ws is too small.
__global__ void mink_prep_w32(const float* __restrict__ w,
                              unsigned short* __restrict__ wf) {
    int t = blockIdx.x * 256 + threadIdx.x;
    if (t >= KK * 4 * 64) return;
    int l = t & 63, ks = (t >> 6) & 3, k = t >> 8;
    int col = l & 31;
    int kb = ks * 16 + (l >> 5) * 4;
    #pragma unroll
    for (int j = 0; j < 8; ++j) {
        int c = kb + (j & 3) + 8 * (j >> 2);
        float v = w[(k * NIN + c) * NOUT + col];
        unsigned short hi = f2bf_rne(v);
        unsigned short lo = f2bf_rne(v - bf2f(hi));
        wf[(size_t)((k * 4 + ks) * 64 + l) * 8 + j] = hi;
        wf[(size_t)(KK * 4 * 64 * 8) + (size_t)((k * 4 + ks) * 64 + l) * 8 + j] = lo;
    }
}

__global__ void mink_init_bias(float4* __restrict__ out,
                               const float4* __restrict__ bias, int n4) {
    int i = blockIdx.x * blockDim.x + threadIdx.x;
    if (i < n4) out[i] = bias[i & 7];
}

__global__ __launch_bounds__(256) void mink_scatter_mfma(
    const float* __restrict__ feats,
    const unsigned short* __restrict__ wf,
    const int* __restrict__ out_idx,
    float* __restrict__ out,
    int ntiles) {
    int wid  = (blockIdx.x * 256 + threadIdx.x) >> 6;
    int lane = threadIdx.x & 63;
    if (wid >= ntiles) return;
    int n0   = wid * 32;
    int half = lane >> 5;
    int col  = lane & 31;

    const float* xrow = feats + (size_t)(n0 + col) * NIN;
    int kbase = half * 4;
    bf16x8 ahi[4], alo[4];
    #pragma unroll
    for (int ks = 0; ks < 4; ++ks) {
        float4 v0 = *(const float4*)(xrow + ks * 16 + kbase);
        float4 v1 = *(const float4*)(xrow + ks * 16 + kbase + 8);
        float xs[8] = {v0.x, v0.y, v0.z, v0.w, v1.x, v1.y, v1.z, v1.w};
        #pragma unroll
        for (int j = 0; j < 8; ++j) {
            unsigned short h = f2bf_rne(xs[j]);
            ahi[ks][j] = (short)h;
            alo[ks][j] = (short)f2bf_rne(xs[j] - bf2f(h));
        }
    }
    const bf16x8* wfh = (const bf16x8*)wf;
    const bf16x8* wfl = wfh + KK * 4 * 64;
    #pragma unroll 1
    for (int k = 0; k < KK; ++k) {
        f32x16 acc = {0,0,0,0,0,0,0,0,0,0,0,0,0,0,0,0};
        #pragma unroll
        for (int ks = 0; ks < 4; ++ks) {
            bf16x8 bh = wfh[(k * 4 + ks) * 64 + lane];
            bf16x8 bl = wfl[(k * 4 + ks) * 64 + lane];
            acc = __builtin_amdgcn_mfma_f32_32x32x16_bf16(ahi[ks], bh, acc, 0, 0, 0);
            acc = __builtin_amdgcn_mfma_f32_32x32x16_bf16(ahi[ks], bl, acc, 0, 0, 0);
            acc = __builtin_amdgcn_mfma_f32_32x32x16_bf16(alo[ks], bh, acc, 0, 0, 0);
        }
        #pragma unroll
        for (int rr = 0; rr < 16; ++rr) {
            int site = (rr & 3) + 8 * (rr >> 2) + 4 * half;
            int row = out_idx[(size_t)(n0 + site) * KK + k];
            unsafeAtomicAdd(out + (size_t)row * NOUT + col, acc[rr]);
        }
    }
}

__global__ void mink_relu(float4* __restrict__ out, int n4) {
    int i = blockIdx.x * blockDim.x + threadIdx.x;
    if (i < n4) {
        float4 v = out[i];
        v.x = fmaxf(v.x, 0.0f);
        v.y = fmaxf(v.y, 0.0f);
        v.z = fmaxf(v.z, 0.0f);
        v.w = fmaxf(v.w, 0.0f);
        out[i] = v;
    }
}

extern "C" void kernel_launch(void* const* d_in, const int* in_sizes, int n_in,
                              void* d_out, int out_size, void* d_ws, size_t ws_size,
                              hipStream_t stream) {
    const float* feats  = (const float*)d_in[0];  // [N, 64] f32
    const float* weight = (const float*)d_in[1];  // [9, 64, 32] f32
    const float* bias   = (const float*)d_in[2];  // [32] f32
    const int*   oidx   = (const int*)d_in[3];    // [N, 9] i32
    float* out = (float*)d_out;                   // [num_out, 32] f32

    int n       = in_sizes[0] / NIN;              // 262144
    int n4      = out_size / 4;
    int num_out = out_size / NOUT;

    // d_ws layout: wf(73728) | repmin[num_out] | inv[9*num_out] | buf[n*64 f32]
    unsigned short* wf = (unsigned short*)d_ws;
    size_t off = 73728;
    int* repmin = (int*)((char*)d_ws + off);  off += (size_t)num_out * 4 + 16;
    off = (off + 255) & ~(size_t)255;
    int* inv    = (int*)((char*)d_ws + off);  off += (size_t)KK * num_out * 4 + 16;
    off = (off + 255) & ~(size_t)255;
    float* buf  = (float*)((char*)d_ws + off); off += (size_t)n * NIN * 4;

    if (off <= ws_size) {
        // ---- inverse-map 16x16 gather path (no output atomics)
        mink_prep_w16<<<(72 * 64 + 255) / 256, 256, 0, stream>>>(weight, wf);

        long long inv4c = ((long long)KK * num_out + 3) / 4;
        long long rep4c = ((long long)num_out + 3) / 4;
        mink_fill<<<1024, 256, 0, stream>>>((int4*)inv, inv4c, -1);
        mink_fill<<<256, 256, 0, stream>>>((int4*)repmin, rep4c, 0x7FFFFFFF);
        mink_rep<<<(n + 255) / 256, 256, 0, stream>>>(oidx, repmin, n);

        long long nthr = (long long)n * NIN;
        mink_copy_reps<<<(int)(nthr / 256), 256, 0, stream>>>(
            feats, oidx, repmin, buf, n);
        mink_dup_accum<<<(int)(nthr / 256), 256, 0, stream>>>(
            feats, oidx, repmin, buf, n);

        mink_pack16<<<(n + 255) / 256, 256, 0, stream>>>(oidx, repmin, buf, n);
        mink_inv4<<<(num_out + 255) / 256, 256, 0, stream>>>(repmin, inv, num_out);
        mink_inv8<<<(n + 255) / 256, 256, 0, stream>>>(oidx, repmin, inv, n, num_out);

        int nwid = (num_out + 15) / 16;
        mink_gather16<<<(nwid + 7) / 8, 512, 0, stream>>>(
            buf, wf, inv, bias, out, num_out);
    } else {
        // ---- fallback: round-4 atomic scatter
        mink_prep_w32<<<(KK * 4 * 64 + 255) / 256, 256, 0, stream>>>(weight, wf);
        mink_init_bias<<<(n4 + 255) / 256, 256, 0, stream>>>(
            (float4*)out, (const float4*)bias, n4);
        int ntiles = n / 32;
        mink_scatter_mfma<<<ntiles * 64 / 256, 256, 0, stream>>>(
            feats, wf, oidx, out, ntiles);
        mink_relu<<<(n4 + 255) / 256, 256, 0, stream>>>((float4*)out, n4);
    }
}

// Round 11
// 252.510 us; speedup vs baseline: 4.3078x; 1.1315x over previous
//
#include <hip/hip_runtime.h>

#define NIN 64
#define NOUT 32
#define KK 9
#define TT 4   // output tiles (of 16 rows) per wave in the gather

typedef __attribute__((ext_vector_type(8))) short bf16x8;
typedef __attribute__((ext_vector_type(4))) float f32x4;
typedef __attribute__((ext_vector_type(16))) float f32x16;
typedef __attribute__((ext_vector_type(8))) unsigned short u16x8;

// fp32 -> bf16 round-to-nearest-even
__device__ __forceinline__ unsigned short f2bf_rne(float f) {
    unsigned int u = __builtin_bit_cast(unsigned int, f);
    unsigned int r = (u + 0x7FFFu + ((u >> 16) & 1u)) >> 16;
    return (unsigned short)r;
}
__device__ __forceinline__ float bf2f(unsigned short h) {
    unsigned int u = ((unsigned int)h) << 16;
    return __builtin_bit_cast(float, u);
}

// ---------------------------------------------------------------------------
// Weights for the 16x16x32 gather: split bf16 hi/lo ON W (x stays single
// bf16). frag id fid = ((k*2+kh)*2+ch)*2+term; elem j of lane l:
//   ch_idx = kh*32 + 16*(j>>2) + (l>>4)*4 + (j&3),  col = ch*16 + (l&15)
__global__ void mink_prep_w16(const float* __restrict__ w,
                              unsigned short* __restrict__ wfB) {
    int t = blockIdx.x * 256 + threadIdx.x;
    if (t >= 72 * 64) return;
    int lane = t & 63, fid = t >> 6;
    int term = fid & 1, ch = (fid >> 1) & 1, kh = (fid >> 2) & 1, k = fid >> 3;
    int g = lane >> 4, col = ch * 16 + (lane & 15);
    #pragma unroll
    for (int j = 0; j < 8; ++j) {
        int ci = kh * 32 + 16 * (j >> 2) + g * 4 + (j & 3);
        float v = w[(k * NIN + ci) * NOUT + col];
        unsigned short hi = f2bf_rne(v);
        unsigned short val = term ? f2bf_rne(v - bf2f(hi)) : hi;
        wfB[(size_t)fid * 512 + lane * 8 + j] = val;
    }
}

// ---------------------------------------------------------------------------
// Generic int fill.
__global__ void mink_fill(int4* __restrict__ p, long long n4, int v) {
    long long i = (long long)blockIdx.x * 256 + threadIdx.x;
    long long stride = (long long)gridDim.x * 256;
    int4 val = {v, v, v, v};
    for (; i < n4; i += stride) p[i] = val;
}

// ---------------------------------------------------------------------------
// Step 1: representative site per cell = min site id sharing the center row.
__global__ void mink_rep(const int* __restrict__ oidx, int* __restrict__ repmin,
                         int n) {
    int i = blockIdx.x * 256 + threadIdx.x;
    if (i < n) atomicMin(&repmin[oidx[(size_t)i * KK + 4]], i);
}

// ---------------------------------------------------------------------------
// Step 2a: rep sites copy features into buf (plain stores, coalesced).
// MUST be a separate launch from dup_accum: the plain store has to be
// globally ordered BEFORE any duplicate's atomicAdd (round-10 fusion raced
// and lost contributions).
__global__ void mink_copy_reps(const float* __restrict__ feats,
                               const int* __restrict__ oidx,
                               const int* __restrict__ repmin,
                               float* __restrict__ buf, int n) {
    int t = blockIdx.x * 256 + threadIdx.x;
    int site = t >> 6;
    if (site >= n) return;
    int rep = repmin[oidx[(size_t)site * KK + 4]];
    if (rep == site) buf[t] = feats[t];
}

// ---------------------------------------------------------------------------
// Step 2b: duplicates add into buf[rep]; wave-coalesced channels -> 4 line
// touches per dup site. Wave-uniform predicate -> rep waves skip the load.
__global__ void mink_dup_accum(const float* __restrict__ feats,
                               const int* __restrict__ oidx,
                               const int* __restrict__ repmin,
                               float* __restrict__ buf, int n) {
    int t = blockIdx.x * 256 + threadIdx.x;
    int site = t >> 6;
    if (site >= n) return;
    int c = t & 63;
    int rep = repmin[oidx[(size_t)site * KK + 4]];
    if (rep != site)
        unsafeAtomicAdd(buf + (size_t)rep * NIN + c, feats[t]);
}

// ---------------------------------------------------------------------------
// Step 3: pack summed fp32 row -> single-bf16 A fragments, in place (128 B
// at the row start). chunk (kh,g) elem j: ch = kh*32 + 16*(j>>2) + g*4 + (j&3)
__global__ void mink_pack16(const int* __restrict__ oidx,
                            const int* __restrict__ repmin,
                            float* __restrict__ buf, int n) {
    int i = blockIdx.x * 256 + threadIdx.x;
    if (i >= n) return;
    if (repmin[oidx[(size_t)i * KK + 4]] != i) return;

    float x[NIN];
    float4* p4 = (float4*)(buf + (size_t)i * NIN);
    #pragma unroll
    for (int j = 0; j < NIN / 4; ++j) {
        float4 v = p4[j];
        x[j * 4 + 0] = v.x; x[j * 4 + 1] = v.y;
        x[j * 4 + 2] = v.z; x[j * 4 + 3] = v.w;
    }
    #pragma unroll
    for (int kh = 0; kh < 2; ++kh) {
        #pragma unroll
        for (int g = 0; g < 4; ++g) {
            u16x8 a;
            #pragma unroll
            for (int j = 0; j < 8; ++j) {
                int c = kh * 32 + 16 * (j >> 2) + g * 4 + (j & 3);
                a[j] = f2bf_rne(x[c]);
            }
            p4[kh * 4 + g] = __builtin_bit_cast(float4, a);
        }
    }
}

// ---------------------------------------------------------------------------
// Step 4a: center plane (k=4) of inv is exactly repmin (INT_MAX -> -1).
__global__ void mink_inv4(const int* __restrict__ repmin, int* __restrict__ inv,
                          int num_out) {
    int r = blockIdx.x * 256 + threadIdx.x;
    if (r < num_out) {
        int v = repmin[r];
        inv[(size_t)4 * num_out + r] = (v == 0x7FFFFFFF) ? -1 : v;
    }
}

// Step 4b: remaining 8 planes (scattered plain stores, reps only).
__global__ void mink_inv8(const int* __restrict__ oidx,
                          const int* __restrict__ repmin,
                          int* __restrict__ inv, int n, int num_out) {
    int i = blockIdx.x * 256 + threadIdx.x;
    if (i >= n) return;
    if (repmin[oidx[(size_t)i * KK + 4]] != i) return;
    #pragma unroll
    for (int k = 0; k < KK; ++k) {
        if (k == 4) continue;
        inv[(size_t)k * num_out + oidx[(size_t)i * KK + k]] = i;
    }
}

// ---------------------------------------------------------------------------
// Step 5: 16x16x32 gather, TT=4 tiles per wave. W (hi+lo) staged in LDS per
// 512-thread block; each B ds_read is shared by 4 output tiles (LDS traffic
// /4 vs round 9); 4 independent acc chains give MFMA ILP. Single coalesced
// store per row, fused bias+ReLU. No atomics.
__global__ __launch_bounds__(512) void mink_gather16(
    const float* __restrict__ buf,          // packed bf16 A rows (128 B used)
    const unsigned short* __restrict__ wfB, // 72 frags x 1 KB
    const int* __restrict__ inv,            // [9][num_out]
    const float* __restrict__ bias,         // [32]
    float* __restrict__ out,                // [num_out, 32]
    int num_out) {
    __shared__ unsigned short wlds[72 * 512];   // 72 KB
    {
        const int4* src = (const int4*)wfB;
        int4* dst = (int4*)wlds;
        for (int i = threadIdx.x; i < 72 * 512 / 8; i += 512) dst[i] = src[i];
    }
    __syncthreads();

    int wid  = (blockIdx.x * 512 + threadIdx.x) >> 6;
    int lane = threadIdx.x & 63;
    int r0   = wid * (16 * TT);
    if (r0 >= num_out) return;
    int g   = lane >> 4;
    int c16 = lane & 15;

    f32x4 acc[TT][2];
    #pragma unroll
    for (int t = 0; t < TT; ++t) {
        acc[t][0] = (f32x4){0, 0, 0, 0};
        acc[t][1] = (f32x4){0, 0, 0, 0};
    }

    #pragma unroll
    for (int k = 0; k < KK; ++k) {
        bf16x8 a0[TT], a1[TT];
        #pragma unroll
        for (int t = 0; t < TT; ++t) {
            int r = r0 + t * 16 + c16;
            int iv = (r < num_out) ? inv[(size_t)k * num_out + r] : -1;
            a0[t] = (bf16x8){0,0,0,0,0,0,0,0};
            a1[t] = (bf16x8){0,0,0,0,0,0,0,0};
            if (iv >= 0) {
                const bf16x8* ab = (const bf16x8*)(buf + (size_t)iv * NIN);
                a0[t] = ab[g];
                a1[t] = ab[4 + g];
            }
        }
        #pragma unroll
        for (int kh = 0; kh < 2; ++kh) {
            #pragma unroll
            for (int ch = 0; ch < 2; ++ch) {
                const unsigned short* p =
                    wlds + (size_t)(((k * 2 + kh) * 2 + ch) * 2) * 512 + lane * 8;
                bf16x8 bh = *(const bf16x8*)p;
                bf16x8 bl = *(const bf16x8*)(p + 512);
                #pragma unroll
                for (int t = 0; t < TT; ++t) {
                    bf16x8 a = kh ? a1[t] : a0[t];
                    acc[t][ch] = __builtin_amdgcn_mfma_f32_16x16x32_bf16(
                        a, bh, acc[t][ch], 0, 0, 0);
                    acc[t][ch] = __builtin_amdgcn_mfma_f32_16x16x32_bf16(
                        a, bl, acc[t][ch], 0, 0, 0);
                }
            }
        }
    }

    // C/D: row = g*4 + reg, col = c16
    #pragma unroll
    for (int t = 0; t < TT; ++t) {
        #pragma unroll
        for (int ch = 0; ch < 2; ++ch) {
            float bb = bias[ch * 16 + c16];
            #pragma unroll
            for (int reg = 0; reg < 4; ++reg) {
                int orow = r0 + t * 16 + g * 4 + reg;
                if (orow < num_out)
                    out[(size_t)orow * NOUT + ch * 16 + c16] =
                        fmaxf(acc[t][ch][reg] + bb, 0.0f);
            }
        }
    }
}

// ---------------------------------------------------------------------------
// Fallback path (round-4 atomic scatter) if d_ws is too small.
__global__ void mink_prep_w32(const float* __restrict__ w,
                              unsigned short* __restrict__ wf) {
    int t = blockIdx.x * 256 + threadIdx.x;
    if (t >= KK * 4 * 64) return;
    int l = t & 63, ks = (t >> 6) & 3, k = t >> 8;
    int col = l & 31;
    int kb = ks * 16 + (l >> 5) * 4;
    #pragma unroll
    for (int j = 0; j < 8; ++j) {
        int c = kb + (j & 3) + 8 * (j >> 2);
        float v = w[(k * NIN + c) * NOUT + col];
        unsigned short hi = f2bf_rne(v);
        unsigned short lo = f2bf_rne(v - bf2f(hi));
        wf[(size_t)((k * 4 + ks) * 64 + l) * 8 + j] = hi;
        wf[(size_t)(KK * 4 * 64 * 8) + (size_t)((k * 4 + ks) * 64 + l) * 8 + j] = lo;
    }
}

__global__ void mink_init_bias(float4* __restrict__ out,
                               const float4* __restrict__ bias, int n4) {
    int i = blockIdx.x * blockDim.x + threadIdx.x;
    if (i < n4) out[i] = bias[i & 7];
}

__global__ __launch_bounds__(256) void mink_scatter_mfma(
    const float* __restrict__ feats,
    const unsigned short* __restrict__ wf,
    const int* __restrict__ out_idx,
    float* __restrict__ out,
    int ntiles) {
    int wid  = (blockIdx.x * 256 + threadIdx.x) >> 6;
    int lane = threadIdx.x & 63;
    if (wid >= ntiles) return;
    int n0   = wid * 32;
    int half = lane >> 5;
    int col  = lane & 31;

    const float* xrow = feats + (size_t)(n0 + col) * NIN;
    int kbase = half * 4;
    bf16x8 ahi[4], alo[4];
    #pragma unroll
    for (int ks = 0; ks < 4; ++ks) {
        float4 v0 = *(const float4*)(xrow + ks * 16 + kbase);
        float4 v1 = *(const float4*)(xrow + ks * 16 + kbase + 8);
        float xs[8] = {v0.x, v0.y, v0.z, v0.w, v1.x, v1.y, v1.z, v1.w};
        #pragma unroll
        for (int j = 0; j < 8; ++j) {
            unsigned short h = f2bf_rne(xs[j]);
            ahi[ks][j] = (short)h;
            alo[ks][j] = (short)f2bf_rne(xs[j] - bf2f(h));
        }
    }
    const bf16x8* wfh = (const bf16x8*)wf;
    const bf16x8* wfl = wfh + KK * 4 * 64;
    #pragma unroll 1
    for (int k = 0; k < KK; ++k) {
        f32x16 acc = {0,0,0,0,0,0,0,0,0,0,0,0,0,0,0,0};
        #pragma unroll
        for (int ks = 0; ks < 4; ++ks) {
            bf16x8 bh = wfh[(k * 4 + ks) * 64 + lane];
            bf16x8 bl = wfl[(k * 4 + ks) * 64 + lane];
            acc = __builtin_amdgcn_mfma_f32_32x32x16_bf16(ahi[ks], bh, acc, 0, 0, 0);
            acc = __builtin_amdgcn_mfma_f32_32x32x16_bf16(ahi[ks], bl, acc, 0, 0, 0);
            acc = __builtin_amdgcn_mfma_f32_32x32x16_bf16(alo[ks], bh, acc, 0, 0, 0);
        }
        #pragma unroll
        for (int rr = 0; rr < 16; ++rr) {
            int site = (rr & 3) + 8 * (rr >> 2) + 4 * half;
            int row = out_idx[(size_t)(n0 + site) * KK + k];
            unsafeAtomicAdd(out + (size_t)row * NOUT + col, acc[rr]);
        }
    }
}

__global__ void mink_relu(float4* __restrict__ out, int n4) {
    int i = blockIdx.x * blockDim.x + threadIdx.x;
    if (i < n4) {
        float4 v = out[i];
        v.x = fmaxf(v.x, 0.0f);
        v.y = fmaxf(v.y, 0.0f);
        v.z = fmaxf(v.z, 0.0f);
        v.w = fmaxf(v.w, 0.0f);
        out[i] = v;
    }
}

extern "C" void kernel_launch(void* const* d_in, const int* in_sizes, int n_in,
                              void* d_out, int out_size, void* d_ws, size_t ws_size,
                              hipStream_t stream) {
    const float* feats  = (const float*)d_in[0];  // [N, 64] f32
    const float* weight = (const float*)d_in[1];  // [9, 64, 32] f32
    const float* bias   = (const float*)d_in[2];  // [32] f32
    const int*   oidx   = (const int*)d_in[3];    // [N, 9] i32
    float* out = (float*)d_out;                   // [num_out, 32] f32

    int n       = in_sizes[0] / NIN;              // 262144
    int n4      = out_size / 4;
    int num_out = out_size / NOUT;

    // d_ws layout: wf(73728) | repmin[num_out] | inv[9*num_out] | buf[n*64 f32]
    unsigned short* wf = (unsigned short*)d_ws;
    size_t off = 73728;
    int* repmin = (int*)((char*)d_ws + off);  off += (size_t)num_out * 4 + 16;
    off = (off + 255) & ~(size_t)255;
    int* inv    = (int*)((char*)d_ws + off);  off += (size_t)KK * num_out * 4 + 16;
    off = (off + 255) & ~(size_t)255;
    float* buf  = (float*)((char*)d_ws + off); off += (size_t)n * NIN * 4;

    if (off <= ws_size) {
        // ---- inverse-map 16x16 gather path (no output atomics)
        mink_prep_w16<<<(72 * 64 + 255) / 256, 256, 0, stream>>>(weight, wf);

        long long inv4c = ((long long)KK * num_out + 3) / 4;
        long long rep4c = ((long long)num_out + 3) / 4;
        mink_fill<<<1024, 256, 0, stream>>>((int4*)inv, inv4c, -1);
        mink_fill<<<256, 256, 0, stream>>>((int4*)repmin, rep4c, 0x7FFFFFFF);
        mink_rep<<<(n + 255) / 256, 256, 0, stream>>>(oidx, repmin, n);

        long long nthr = (long long)n * NIN;
        mink_copy_reps<<<(int)(nthr / 256), 256, 0, stream>>>(
            feats, oidx, repmin, buf, n);
        mink_dup_accum<<<(int)(nthr / 256), 256, 0, stream>>>(
            feats, oidx, repmin, buf, n);

        mink_pack16<<<(n + 255) / 256, 256, 0, stream>>>(oidx, repmin, buf, n);
        mink_inv4<<<(num_out + 255) / 256, 256, 0, stream>>>(repmin, inv, num_out);
        mink_inv8<<<(n + 255) / 256, 256, 0, stream>>>(oidx, repmin, inv, n, num_out);

        int nwave = (num_out + 16 * TT - 1) / (16 * TT);
        mink_gather16<<<(nwave + 7) / 8, 512, 0, stream>>>(
            buf, wf, inv, bias, out, num_out);
    } else {
        // ---- fallback: round-4 atomic scatter
        mink_prep_w32<<<(KK * 4 * 64 + 255) / 256, 256, 0, stream>>>(weight, wf);
        mink_init_bias<<<(n4 + 255) / 256, 256, 0, stream>>>(
            (float4*)out, (const float4*)bias, n4);
        int ntiles = n / 32;
        mink_scatter_mfma<<<ntiles * 64 / 256, 256, 0, stream>>>(
            feats, wf, oidx, out, ntiles);
        mink_relu<<<(n4 + 255) / 256, 256, 0, stream>>>((float4*)out, n4);
    }
}

// Round 12
// 236.867 us; speedup vs baseline: 4.5923x; 1.0660x over previous
//
#include <hip/hip_runtime.h>

#define NIN 64
#define NOUT 32
#define KK 9
#define TT 4   // output tiles (of 16 rows) per wave in the gather

typedef __attribute__((ext_vector_type(8))) short bf16x8;
typedef __attribute__((ext_vector_type(4))) float f32x4;
typedef __attribute__((ext_vector_type(16))) float f32x16;
typedef __attribute__((ext_vector_type(8))) unsigned short u16x8;

// fp32 -> bf16 round-to-nearest-even
__device__ __forceinline__ unsigned short f2bf_rne(float f) {
    unsigned int u = __builtin_bit_cast(unsigned int, f);
    unsigned int r = (u + 0x7FFFu + ((u >> 16) & 1u)) >> 16;
    return (unsigned short)r;
}
__device__ __forceinline__ float bf2f(unsigned short h) {
    unsigned int u = ((unsigned int)h) << 16;
    return __builtin_bit_cast(float, u);
}

// ---------------------------------------------------------------------------
// Weights for the 16x16x32 gather: split bf16 hi/lo ON W (x stays single
// bf16). frag id fid = ((k*2+kh)*2+ch)*2+term; elem j of lane l:
//   ch_idx = kh*32 + 16*(j>>2) + (l>>4)*4 + (j&3),  col = ch*16 + (l&15)
__global__ void mink_prep_w16(const float* __restrict__ w,
                              unsigned short* __restrict__ wfB) {
    int t = blockIdx.x * 256 + threadIdx.x;
    if (t >= 72 * 64) return;
    int lane = t & 63, fid = t >> 6;
    int term = fid & 1, ch = (fid >> 1) & 1, kh = (fid >> 2) & 1, k = fid >> 3;
    int g = lane >> 4, col = ch * 16 + (lane & 15);
    #pragma unroll
    for (int j = 0; j < 8; ++j) {
        int ci = kh * 32 + 16 * (j >> 2) + g * 4 + (j & 3);
        float v = w[(k * NIN + ci) * NOUT + col];
        unsigned short hi = f2bf_rne(v);
        unsigned short val = term ? f2bf_rne(v - bf2f(hi)) : hi;
        wfB[(size_t)fid * 512 + lane * 8 + j] = val;
    }
}

// ---------------------------------------------------------------------------
// Generic int fill.
__global__ void mink_fill(int4* __restrict__ p, long long n4, int v) {
    long long i = (long long)blockIdx.x * 256 + threadIdx.x;
    long long stride = (long long)gridDim.x * 256;
    int4 val = {v, v, v, v};
    for (; i < n4; i += stride) p[i] = val;
}

// ---------------------------------------------------------------------------
// Step 1: representative site per cell = min site id sharing the center row.
__global__ void mink_rep(const int* __restrict__ oidx, int* __restrict__ repmin,
                         int n) {
    int i = blockIdx.x * 256 + threadIdx.x;
    if (i < n) atomicMin(&repmin[oidx[(size_t)i * KK + 4]], i);
}

// ---------------------------------------------------------------------------
// Step 2a: rep sites copy features into buf (plain stores, coalesced).
// MUST stay a separate launch from dup_accum (round-10 fusion raced).
__global__ void mink_copy_reps(const float* __restrict__ feats,
                               const int* __restrict__ oidx,
                               const int* __restrict__ repmin,
                               float* __restrict__ buf, int n) {
    int t = blockIdx.x * 256 + threadIdx.x;
    int site = t >> 6;
    if (site >= n) return;
    int rep = repmin[oidx[(size_t)site * KK + 4]];
    if (rep == site) buf[t] = feats[t];
}

// ---------------------------------------------------------------------------
// Step 2b: duplicates add into buf[rep]; wave-coalesced channels -> 4 line
// touches per dup site.
__global__ void mink_dup_accum(const float* __restrict__ feats,
                               const int* __restrict__ oidx,
                               const int* __restrict__ repmin,
                               float* __restrict__ buf, int n) {
    int t = blockIdx.x * 256 + threadIdx.x;
    int site = t >> 6;
    if (site >= n) return;
    int c = t & 63;
    int rep = repmin[oidx[(size_t)site * KK + 4]];
    if (rep != site)
        unsafeAtomicAdd(buf + (size_t)rep * NIN + c, feats[t]);
}

// ---------------------------------------------------------------------------
// Step 3: pack summed fp32 row -> single-bf16 A fragments, in place (128 B
// at the row start). chunk (kh,g) elem j: ch = kh*32 + 16*(j>>2) + g*4 + (j&3)
__global__ void mink_pack16(const int* __restrict__ oidx,
                            const int* __restrict__ repmin,
                            float* __restrict__ buf, int n) {
    int i = blockIdx.x * 256 + threadIdx.x;
    if (i >= n) return;
    if (repmin[oidx[(size_t)i * KK + 4]] != i) return;

    float x[NIN];
    float4* p4 = (float4*)(buf + (size_t)i * NIN);
    #pragma unroll
    for (int j = 0; j < NIN / 4; ++j) {
        float4 v = p4[j];
        x[j * 4 + 0] = v.x; x[j * 4 + 1] = v.y;
        x[j * 4 + 2] = v.z; x[j * 4 + 3] = v.w;
    }
    #pragma unroll
    for (int kh = 0; kh < 2; ++kh) {
        #pragma unroll
        for (int g = 0; g < 4; ++g) {
            u16x8 a;
            #pragma unroll
            for (int j = 0; j < 8; ++j) {
                int c = kh * 32 + 16 * (j >> 2) + g * 4 + (j & 3);
                a[j] = f2bf_rne(x[c]);
            }
            p4[kh * 4 + g] = __builtin_bit_cast(float4, a);
        }
    }
}

// ---------------------------------------------------------------------------
// Step 4: inverse maps built in OUTPUT-ROW order (round 12). One thread per
// output row r; rep = repmin[r]. For fixed k, r -> oidx[rep][k] is
// near-monotonic (sorted coordinate keys; constant key shift per k), so
// consecutive valid r's write near-consecutive addresses -> ~4 lines per
// 64-row wave per plane instead of 1 line per store (site-order round 11:
// ~1.3M line touches ~= 70 us; this: ~0.5M ~= 30-40 us). Values identical.
__global__ void mink_invr(const int* __restrict__ oidx,
                          const int* __restrict__ repmin,
                          int* __restrict__ inv, int num_out) {
    int r = blockIdx.x * 256 + threadIdx.x;
    if (r >= num_out) return;
    int rep = repmin[r];
    if (rep == 0x7FFFFFFF) return;   // not a center row; planes pre-filled -1
    const int* ip = oidx + (size_t)rep * KK;
    #pragma unroll
    for (int k = 0; k < KK; ++k) {
        int row = (k == 4) ? r : ip[k];
        inv[(size_t)k * num_out + row] = rep;
    }
}

// ---------------------------------------------------------------------------
// Step 5: 16x16x32 gather, TT=4 tiles per wave. W (hi+lo) staged in LDS per
// 512-thread block; each B ds_read shared by 4 output tiles; 4 independent
// acc chains. Single coalesced store per row, fused bias+ReLU. No atomics.
__global__ __launch_bounds__(512) void mink_gather16(
    const float* __restrict__ buf,          // packed bf16 A rows (128 B used)
    const unsigned short* __restrict__ wfB, // 72 frags x 1 KB
    const int* __restrict__ inv,            // [9][num_out]
    const float* __restrict__ bias,         // [32]
    float* __restrict__ out,                // [num_out, 32]
    int num_out) {
    __shared__ unsigned short wlds[72 * 512];   // 72 KB
    {
        const int4* src = (const int4*)wfB;
        int4* dst = (int4*)wlds;
        for (int i = threadIdx.x; i < 72 * 512 / 8; i += 512) dst[i] = src[i];
    }
    __syncthreads();

    int wid  = (blockIdx.x * 512 + threadIdx.x) >> 6;
    int lane = threadIdx.x & 63;
    int r0   = wid * (16 * TT);
    if (r0 >= num_out) return;
    int g   = lane >> 4;
    int c16 = lane & 15;

    f32x4 acc[TT][2];
    #pragma unroll
    for (int t = 0; t < TT; ++t) {
        acc[t][0] = (f32x4){0, 0, 0, 0};
        acc[t][1] = (f32x4){0, 0, 0, 0};
    }

    #pragma unroll
    for (int k = 0; k < KK; ++k) {
        bf16x8 a0[TT], a1[TT];
        #pragma unroll
        for (int t = 0; t < TT; ++t) {
            int r = r0 + t * 16 + c16;
            int iv = (r < num_out) ? inv[(size_t)k * num_out + r] : -1;
            a0[t] = (bf16x8){0,0,0,0,0,0,0,0};
            a1[t] = (bf16x8){0,0,0,0,0,0,0,0};
            if (iv >= 0) {
                const bf16x8* ab = (const bf16x8*)(buf + (size_t)iv * NIN);
                a0[t] = ab[g];
                a1[t] = ab[4 + g];
            }
        }
        #pragma unroll
        for (int kh = 0; kh < 2; ++kh) {
            #pragma unroll
            for (int ch = 0; ch < 2; ++ch) {
                const unsigned short* p =
                    wlds + (size_t)(((k * 2 + kh) * 2 + ch) * 2) * 512 + lane * 8;
                bf16x8 bh = *(const bf16x8*)p;
                bf16x8 bl = *(const bf16x8*)(p + 512);
                #pragma unroll
                for (int t = 0; t < TT; ++t) {
                    bf16x8 a = kh ? a1[t] : a0[t];
                    acc[t][ch] = __builtin_amdgcn_mfma_f32_16x16x32_bf16(
                        a, bh, acc[t][ch], 0, 0, 0);
                    acc[t][ch] = __builtin_amdgcn_mfma_f32_16x16x32_bf16(
                        a, bl, acc[t][ch], 0, 0, 0);
                }
            }
        }
    }

    // C/D: row = g*4 + reg, col = c16
    #pragma unroll
    for (int t = 0; t < TT; ++t) {
        #pragma unroll
        for (int ch = 0; ch < 2; ++ch) {
            float bb = bias[ch * 16 + c16];
            #pragma unroll
            for (int reg = 0; reg < 4; ++reg) {
                int orow = r0 + t * 16 + g * 4 + reg;
                if (orow < num_out)
                    out[(size_t)orow * NOUT + ch * 16 + c16] =
                        fmaxf(acc[t][ch][reg] + bb, 0.0f);
            }
        }
    }
}

// ---------------------------------------------------------------------------
// Fallback path (round-4 atomic scatter) if d_ws is too small.
__global__ void mink_prep_w32(const float* __restrict__ w,
                              unsigned short* __restrict__ wf) {
    int t = blockIdx.x * 256 + threadIdx.x;
    if (t >= KK * 4 * 64) return;
    int l = t & 63, ks = (t >> 6) & 3, k = t >> 8;
    int col = l & 31;
    int kb = ks * 16 + (l >> 5) * 4;
    #pragma unroll
    for (int j = 0; j < 8; ++j) {
        int c = kb + (j & 3) + 8 * (j >> 2);
        float v = w[(k * NIN + c) * NOUT + col];
        unsigned short hi = f2bf_rne(v);
        unsigned short lo = f2bf_rne(v - bf2f(hi));
        wf[(size_t)((k * 4 + ks) * 64 + l) * 8 + j] = hi;
        wf[(size_t)(KK * 4 * 64 * 8) + (size_t)((k * 4 + ks) * 64 + l) * 8 + j] = lo;
    }
}

__global__ void mink_init_bias(float4* __restrict__ out,
                               const float4* __restrict__ bias, int n4) {
    int i = blockIdx.x * blockDim.x + threadIdx.x;
    if (i < n4) out[i] = bias[i & 7];
}

__global__ __launch_bounds__(256) void mink_scatter_mfma(
    const float* __restrict__ feats,
    const unsigned short* __restrict__ wf,
    const int* __restrict__ out_idx,
    float* __restrict__ out,
    int ntiles) {
    int wid  = (blockIdx.x * 256 + threadIdx.x) >> 6;
    int lane = threadIdx.x & 63;
    if (wid >= ntiles) return;
    int n0   = wid * 32;
    int half = lane >> 5;
    int col  = lane & 31;

    const float* xrow = feats + (size_t)(n0 + col) * NIN;
    int kbase = half * 4;
    bf16x8 ahi[4], alo[4];
    #pragma unroll
    for (int ks = 0; ks < 4; ++ks) {
        float4 v0 = *(const float4*)(xrow + ks * 16 + kbase);
        float4 v1 = *(const float4*)(xrow + ks * 16 + kbase + 8);
        float xs[8] = {v0.x, v0.y, v0.z, v0.w, v1.x, v1.y, v1.z, v1.w};
        #pragma unroll
        for (int j = 0; j < 8; ++j) {
            unsigned short h = f2bf_rne(xs[j]);
            ahi[ks][j] = (short)h;
            alo[ks][j] = (short)f2bf_rne(xs[j] - bf2f(h));
        }
    }
    const bf16x8* wfh = (const bf16x8*)wf;
    const bf16x8* wfl = wfh + KK * 4 * 64;
    #pragma unroll 1
    for (int k = 0; k < KK; ++k) {
        f32x16 acc = {0,0,0,0,0,0,0,0,0,0,0,0,0,0,0,0};
        #pragma unroll
        for (int ks = 0; ks < 4; ++ks) {
            bf16x8 bh = wfh[(k * 4 + ks) * 64 + lane];
            bf16x8 bl = wfl[(k * 4 + ks) * 64 + lane];
            acc = __builtin_amdgcn_mfma_f32_32x32x16_bf16(ahi[ks], bh, acc, 0, 0, 0);
            acc = __builtin_amdgcn_mfma_f32_32x32x16_bf16(ahi[ks], bl, acc, 0, 0, 0);
            acc = __builtin_amdgcn_mfma_f32_32x32x16_bf16(alo[ks], bh, acc, 0, 0, 0);
        }
        #pragma unroll
        for (int rr = 0; rr < 16; ++rr) {
            int site = (rr & 3) + 8 * (rr >> 2) + 4 * half;
            int row = out_idx[(size_t)(n0 + site) * KK + k];
            unsafeAtomicAdd(out + (size_t)row * NOUT + col, acc[rr]);
        }
    }
}

__global__ void mink_relu(float4* __restrict__ out, int n4) {
    int i = blockIdx.x * blockDim.x + threadIdx.x;
    if (i < n4) {
        float4 v = out[i];
        v.x = fmaxf(v.x, 0.0f);
        v.y = fmaxf(v.y, 0.0f);
        v.z = fmaxf(v.z, 0.0f);
        v.w = fmaxf(v.w, 0.0f);
        out[i] = v;
    }
}

extern "C" void kernel_launch(void* const* d_in, const int* in_sizes, int n_in,
                              void* d_out, int out_size, void* d_ws, size_t ws_size,
                              hipStream_t stream) {
    const float* feats  = (const float*)d_in[0];  // [N, 64] f32
    const float* weight = (const float*)d_in[1];  // [9, 64, 32] f32
    const float* bias   = (const float*)d_in[2];  // [32] f32
    const int*   oidx   = (const int*)d_in[3];    // [N, 9] i32
    float* out = (float*)d_out;                   // [num_out, 32] f32

    int n       = in_sizes[0] / NIN;              // 262144
    int n4      = out_size / 4;
    int num_out = out_size / NOUT;

    // d_ws layout: wf(73728) | repmin[num_out] | inv[9*num_out] | buf[n*64 f32]
    unsigned short* wf = (unsigned short*)d_ws;
    size_t off = 73728;
    int* repmin = (int*)((char*)d_ws + off);  off += (size_t)num_out * 4 + 16;
    off = (off + 255) & ~(size_t)255;
    int* inv    = (int*)((char*)d_ws + off);  off += (size_t)KK * num_out * 4 + 16;
    off = (off + 255) & ~(size_t)255;
    float* buf  = (float*)((char*)d_ws + off); off += (size_t)n * NIN * 4;

    if (off <= ws_size) {
        // ---- inverse-map 16x16 gather path (no output atomics)
        mink_prep_w16<<<(72 * 64 + 255) / 256, 256, 0, stream>>>(weight, wf);

        long long inv4c = ((long long)KK * num_out + 3) / 4;
        long long rep4c = ((long long)num_out + 3) / 4;
        mink_fill<<<1024, 256, 0, stream>>>((int4*)inv, inv4c, -1);
        mink_fill<<<256, 256, 0, stream>>>((int4*)repmin, rep4c, 0x7FFFFFFF);
        mink_rep<<<(n + 255) / 256, 256, 0, stream>>>(oidx, repmin, n);

        long long nthr = (long long)n * NIN;
        mink_copy_reps<<<(int)(nthr / 256), 256, 0, stream>>>(
            feats, oidx, repmin, buf, n);
        mink_dup_accum<<<(int)(nthr / 256), 256, 0, stream>>>(
            feats, oidx, repmin, buf, n);

        mink_pack16<<<(n + 255) / 256, 256, 0, stream>>>(oidx, repmin, buf, n);
        mink_invr<<<(num_out + 255) / 256, 256, 0, stream>>>(
            oidx, repmin, inv, num_out);

        int nwave = (num_out + 16 * TT - 1) / (16 * TT);
        mink_gather16<<<(nwave + 7) / 8, 512, 0, stream>>>(
            buf, wf, inv, bias, out, num_out);
    } else {
        // ---- fallback: round-4 atomic scatter
        mink_prep_w32<<<(KK * 4 * 64 + 255) / 256, 256, 0, stream>>>(weight, wf);
        mink_init_bias<<<(n4 + 255) / 256, 256, 0, stream>>>(
            (float4*)out, (const float4*)bias, n4);
        int ntiles = n / 32;
        mink_scatter_mfma<<<ntiles * 64 / 256, 256, 0, stream>>>(
            feats, wf, oidx, out, ntiles);
        mink_relu<<<(n4 + 255) / 256, 256, 0, stream>>>((float4*)out, n4);
    }
}

// Round 13
// 208.842 us; speedup vs baseline: 5.2086x; 1.1342x over previous
//
#include <hip/hip_runtime.h>

#define NIN 64
#define NOUT 32
#define KK 9
#define TT 4   // output tiles (of 16 rows) per wave in the gather

typedef __attribute__((ext_vector_type(8))) short bf16x8;
typedef __attribute__((ext_vector_type(4))) float f32x4;
typedef __attribute__((ext_vector_type(16))) float f32x16;
typedef __attribute__((ext_vector_type(8))) unsigned short u16x8;

// fp32 -> bf16 round-to-nearest-even
__device__ __forceinline__ unsigned short f2bf_rne(float f) {
    unsigned int u = __builtin_bit_cast(unsigned int, f);
    unsigned int r = (u + 0x7FFFu + ((u >> 16) & 1u)) >> 16;
    return (unsigned short)r;
}
__device__ __forceinline__ float bf2f(unsigned short h) {
    unsigned int u = ((unsigned int)h) << 16;
    return __builtin_bit_cast(float, u);
}

// ---------------------------------------------------------------------------
// Weights for the 16x16x32 gather: SINGLE bf16 (round 13: dropped the lo
// term; W-rounding error ~ x-rounding error, absmax budget 0.12 >> ~0.06).
// frag id fid = (k*2+kh)*2+ch; elem j of lane l:
//   ch_idx = kh*32 + 16*(j>>2) + (l>>4)*4 + (j&3),  col = ch*16 + (l&15)
__global__ void mink_prep_w16(const float* __restrict__ w,
                              unsigned short* __restrict__ wfB) {
    int t = blockIdx.x * 256 + threadIdx.x;
    if (t >= 36 * 64) return;
    int lane = t & 63, fid = t >> 6;
    int ch = fid & 1, kh = (fid >> 1) & 1, k = fid >> 2;
    int g = lane >> 4, col = ch * 16 + (lane & 15);
    #pragma unroll
    for (int j = 0; j < 8; ++j) {
        int ci = kh * 32 + 16 * (j >> 2) + g * 4 + (j & 3);
        wfB[(size_t)fid * 512 + lane * 8 + j] =
            f2bf_rne(w[(k * NIN + ci) * NOUT + col]);
    }
}

// ---------------------------------------------------------------------------
// Generic int fill.
__global__ void mink_fill(int4* __restrict__ p, long long n4, int v) {
    long long i = (long long)blockIdx.x * 256 + threadIdx.x;
    long long stride = (long long)gridDim.x * 256;
    int4 val = {v, v, v, v};
    for (; i < n4; i += stride) p[i] = val;
}

// ---------------------------------------------------------------------------
// Step 1: representative site per cell = min site id sharing the center row.
__global__ void mink_rep(const int* __restrict__ oidx, int* __restrict__ repmin,
                         int n) {
    int i = blockIdx.x * 256 + threadIdx.x;
    if (i < n) atomicMin(&repmin[oidx[(size_t)i * KK + 4]], i);
}

// ---------------------------------------------------------------------------
// Step 1b (round 13): materialize rep_of[site] once. The scattered
// repmin[oidx[site][4]] lookup was repeated in copy/dup/pack (~14 us each);
// now one scattered pass + sequential 1 MB streams for all consumers.
__global__ void mink_resolve(const int* __restrict__ oidx,
                             const int* __restrict__ repmin,
                             int* __restrict__ rep_of, int n) {
    int i = blockIdx.x * 256 + threadIdx.x;
    if (i < n) rep_of[i] = repmin[oidx[(size_t)i * KK + 4]];
}

// ---------------------------------------------------------------------------
// Step 2a: rep sites copy features into buf (plain stores, coalesced).
// MUST stay a separate launch from dup_accum (round-10 fusion raced).
__global__ void mink_copy_reps(const float* __restrict__ feats,
                               const int* __restrict__ rep_of,
                               float* __restrict__ buf, int n) {
    int t = blockIdx.x * 256 + threadIdx.x;
    int site = t >> 6;
    if (site >= n) return;
    if (rep_of[site] == site) buf[t] = feats[t];
}

// ---------------------------------------------------------------------------
// Step 2b: duplicates add into buf[rep]; wave-coalesced channels -> 4 line
// touches per dup site.
__global__ void mink_dup_accum(const float* __restrict__ feats,
                               const int* __restrict__ rep_of,
                               float* __restrict__ buf, int n) {
    int t = blockIdx.x * 256 + threadIdx.x;
    int site = t >> 6;
    if (site >= n) return;
    int rep = rep_of[site];
    if (rep != site)
        unsafeAtomicAdd(buf + (size_t)rep * NIN + (t & 63), feats[t]);
}

// ---------------------------------------------------------------------------
// Step 3: pack summed fp32 row -> single-bf16 A fragments, in place (128 B
// at the row start). chunk (kh,g) elem j: ch = kh*32 + 16*(j>>2) + g*4 + (j&3)
__global__ void mink_pack16(const int* __restrict__ rep_of,
                            float* __restrict__ buf, int n) {
    int i = blockIdx.x * 256 + threadIdx.x;
    if (i >= n) return;
    if (rep_of[i] != i) return;

    float x[NIN];
    float4* p4 = (float4*)(buf + (size_t)i * NIN);
    #pragma unroll
    for (int j = 0; j < NIN / 4; ++j) {
        float4 v = p4[j];
        x[j * 4 + 0] = v.x; x[j * 4 + 1] = v.y;
        x[j * 4 + 2] = v.z; x[j * 4 + 3] = v.w;
    }
    #pragma unroll
    for (int kh = 0; kh < 2; ++kh) {
        #pragma unroll
        for (int g = 0; g < 4; ++g) {
            u16x8 a;
            #pragma unroll
            for (int j = 0; j < 8; ++j) {
                int c = kh * 32 + 16 * (j >> 2) + g * 4 + (j & 3);
                a[j] = f2bf_rne(x[c]);
            }
            p4[kh * 4 + g] = __builtin_bit_cast(float4, a);
        }
    }
}

// ---------------------------------------------------------------------------
// Step 4: inverse maps in output-row order (round 12: near-monotonic writes).
__global__ void mink_invr(const int* __restrict__ oidx,
                          const int* __restrict__ repmin,
                          int* __restrict__ inv, int num_out) {
    int r = blockIdx.x * 256 + threadIdx.x;
    if (r >= num_out) return;
    int rep = repmin[r];
    if (rep == 0x7FFFFFFF) return;   // not a center row; planes pre-filled -1
    const int* ip = oidx + (size_t)rep * KK;
    #pragma unroll
    for (int k = 0; k < KK; ++k) {
        int row = (k == 4) ? r : ip[k];
        inv[(size_t)k * num_out + row] = rep;
    }
}

// ---------------------------------------------------------------------------
// Step 5: 16x16x32 gather, TT=4 tiles per wave, single-bf16 W. LDS is now
// 36 KB -> 4 blocks/CU (was 2 at 72 KB), 4 MFMA per k (was 8). Single
// coalesced store per row, fused bias+ReLU. No atomics.
__global__ __launch_bounds__(512) void mink_gather16(
    const float* __restrict__ buf,          // packed bf16 A rows (128 B used)
    const unsigned short* __restrict__ wfB, // 36 frags x 1 KB
    const int* __restrict__ inv,            // [9][num_out]
    const float* __restrict__ bias,         // [32]
    float* __restrict__ out,                // [num_out, 32]
    int num_out) {
    __shared__ unsigned short wlds[36 * 512];   // 36 KB
    {
        const int4* src = (const int4*)wfB;
        int4* dst = (int4*)wlds;
        for (int i = threadIdx.x; i < 36 * 512 / 8; i += 512) dst[i] = src[i];
    }
    __syncthreads();

    int wid  = (blockIdx.x * 512 + threadIdx.x) >> 6;
    int lane = threadIdx.x & 63;
    int r0   = wid * (16 * TT);
    if (r0 >= num_out) return;
    int g   = lane >> 4;
    int c16 = lane & 15;

    f32x4 acc[TT][2];
    #pragma unroll
    for (int t = 0; t < TT; ++t) {
        acc[t][0] = (f32x4){0, 0, 0, 0};
        acc[t][1] = (f32x4){0, 0, 0, 0};
    }

    #pragma unroll
    for (int k = 0; k < KK; ++k) {
        bf16x8 a0[TT], a1[TT];
        #pragma unroll
        for (int t = 0; t < TT; ++t) {
            int r = r0 + t * 16 + c16;
            int iv = (r < num_out) ? inv[(size_t)k * num_out + r] : -1;
            a0[t] = (bf16x8){0,0,0,0,0,0,0,0};
            a1[t] = (bf16x8){0,0,0,0,0,0,0,0};
            if (iv >= 0) {
                const bf16x8* ab = (const bf16x8*)(buf + (size_t)iv * NIN);
                a0[t] = ab[g];
                a1[t] = ab[4 + g];
            }
        }
        #pragma unroll
        for (int kh = 0; kh < 2; ++kh) {
            #pragma unroll
            for (int ch = 0; ch < 2; ++ch) {
                bf16x8 b = *(const bf16x8*)(
                    wlds + (size_t)((k * 2 + kh) * 2 + ch) * 512 + lane * 8);
                #pragma unroll
                for (int t = 0; t < TT; ++t) {
                    bf16x8 a = kh ? a1[t] : a0[t];
                    acc[t][ch] = __builtin_amdgcn_mfma_f32_16x16x32_bf16(
                        a, b, acc[t][ch], 0, 0, 0);
                }
            }
        }
    }

    // C/D: row = g*4 + reg, col = c16
    #pragma unroll
    for (int t = 0; t < TT; ++t) {
        #pragma unroll
        for (int ch = 0; ch < 2; ++ch) {
            float bb = bias[ch * 16 + c16];
            #pragma unroll
            for (int reg = 0; reg < 4; ++reg) {
                int orow = r0 + t * 16 + g * 4 + reg;
                if (orow < num_out)
                    out[(size_t)orow * NOUT + ch * 16 + c16] =
                        fmaxf(acc[t][ch][reg] + bb, 0.0f);
            }
        }
    }
}

// ---------------------------------------------------------------------------
// Fallback path (round-4 atomic scatter) if d_ws is too small.
__global__ void mink_prep_w32(const float* __restrict__ w,
                              unsigned short* __restrict__ wf) {
    int t = blockIdx.x * 256 + threadIdx.x;
    if (t >= KK * 4 * 64) return;
    int l = t & 63, ks = (t >> 6) & 3, k = t >> 8;
    int col = l & 31;
    int kb = ks * 16 + (l >> 5) * 4;
    #pragma unroll
    for (int j = 0; j < 8; ++j) {
        int c = kb + (j & 3) + 8 * (j >> 2);
        float v = w[(k * NIN + c) * NOUT + col];
        unsigned short hi = f2bf_rne(v);
        unsigned short lo = f2bf_rne(v - bf2f(hi));
        wf[(size_t)((k * 4 + ks) * 64 + l) * 8 + j] = hi;
        wf[(size_t)(KK * 4 * 64 * 8) + (size_t)((k * 4 + ks) * 64 + l) * 8 + j] = lo;
    }
}

__global__ void mink_init_bias(float4* __restrict__ out,
                               const float4* __restrict__ bias, int n4) {
    int i = blockIdx.x * blockDim.x + threadIdx.x;
    if (i < n4) out[i] = bias[i & 7];
}

__global__ __launch_bounds__(256) void mink_scatter_mfma(
    const float* __restrict__ feats,
    const unsigned short* __restrict__ wf,
    const int* __restrict__ out_idx,
    float* __restrict__ out,
    int ntiles) {
    int wid  = (blockIdx.x * 256 + threadIdx.x) >> 6;
    int lane = threadIdx.x & 63;
    if (wid >= ntiles) return;
    int n0   = wid * 32;
    int half = lane >> 5;
    int col  = lane & 31;

    const float* xrow = feats + (size_t)(n0 + col) * NIN;
    int kbase = half * 4;
    bf16x8 ahi[4], alo[4];
    #pragma unroll
    for (int ks = 0; ks < 4; ++ks) {
        float4 v0 = *(const float4*)(xrow + ks * 16 + kbase);
        float4 v1 = *(const float4*)(xrow + ks * 16 + kbase + 8);
        float xs[8] = {v0.x, v0.y, v0.z, v0.w, v1.x, v1.y, v1.z, v1.w};
        #pragma unroll
        for (int j = 0; j < 8; ++j) {
            unsigned short h = f2bf_rne(xs[j]);
            ahi[ks][j] = (short)h;
            alo[ks][j] = (short)f2bf_rne(xs[j] - bf2f(h));
        }
    }
    const bf16x8* wfh = (const bf16x8*)wf;
    const bf16x8* wfl = wfh + KK * 4 * 64;
    #pragma unroll 1
    for (int k = 0; k < KK; ++k) {
        f32x16 acc = {0,0,0,0,0,0,0,0,0,0,0,0,0,0,0,0};
        #pragma unroll
        for (int ks = 0; ks < 4; ++ks) {
            bf16x8 bh = wfh[(k * 4 + ks) * 64 + lane];
            bf16x8 bl = wfl[(k * 4 + ks) * 64 + lane];
            acc = __builtin_amdgcn_mfma_f32_32x32x16_bf16(ahi[ks], bh, acc, 0, 0, 0);
            acc = __builtin_amdgcn_mfma_f32_32x32x16_bf16(ahi[ks], bl, acc, 0, 0, 0);
            acc = __builtin_amdgcn_mfma_f32_32x32x16_bf16(alo[ks], bh, acc, 0, 0, 0);
        }
        #pragma unroll
        for (int rr = 0; rr < 16; ++rr) {
            int site = (rr & 3) + 8 * (rr >> 2) + 4 * half;
            int row = out_idx[(size_t)(n0 + site) * KK + k];
            unsafeAtomicAdd(out + (size_t)row * NOUT + col, acc[rr]);
        }
    }
}

__global__ void mink_relu(float4* __restrict__ out, int n4) {
    int i = blockIdx.x * blockDim.x + threadIdx.x;
    if (i < n4) {
        float4 v = out[i];
        v.x = fmaxf(v.x, 0.0f);
        v.y = fmaxf(v.y, 0.0f);
        v.z = fmaxf(v.z, 0.0f);
        v.w = fmaxf(v.w, 0.0f);
        out[i] = v;
    }
}

extern "C" void kernel_launch(void* const* d_in, const int* in_sizes, int n_in,
                              void* d_out, int out_size, void* d_ws, size_t ws_size,
                              hipStream_t stream) {
    const float* feats  = (const float*)d_in[0];  // [N, 64] f32
    const float* weight = (const float*)d_in[1];  // [9, 64, 32] f32
    const float* bias   = (const float*)d_in[2];  // [32] f32
    const int*   oidx   = (const int*)d_in[3];    // [N, 9] i32
    float* out = (float*)d_out;                   // [num_out, 32] f32

    int n       = in_sizes[0] / NIN;              // 262144
    int n4      = out_size / 4;
    int num_out = out_size / NOUT;

    // d_ws layout: wf(73728 reserved) | repmin | rep_of[n] | inv | buf
    unsigned short* wf = (unsigned short*)d_ws;
    size_t off = 73728;
    int* repmin = (int*)((char*)d_ws + off);  off += (size_t)num_out * 4 + 16;
    off = (off + 255) & ~(size_t)255;
    int* rep_of = (int*)((char*)d_ws + off);  off += (size_t)n * 4;
    off = (off + 255) & ~(size_t)255;
    int* inv    = (int*)((char*)d_ws + off);  off += (size_t)KK * num_out * 4 + 16;
    off = (off + 255) & ~(size_t)255;
    float* buf  = (float*)((char*)d_ws + off); off += (size_t)n * NIN * 4;

    if (off <= ws_size) {
        // ---- inverse-map 16x16 gather path (no output atomics)
        mink_prep_w16<<<(36 * 64 + 255) / 256, 256, 0, stream>>>(weight, wf);

        long long inv4c = ((long long)KK * num_out + 3) / 4;
        long long rep4c = ((long long)num_out + 3) / 4;
        mink_fill<<<1024, 256, 0, stream>>>((int4*)inv, inv4c, -1);
        mink_fill<<<256, 256, 0, stream>>>((int4*)repmin, rep4c, 0x7FFFFFFF);
        mink_rep<<<(n + 255) / 256, 256, 0, stream>>>(oidx, repmin, n);
        mink_resolve<<<(n + 255) / 256, 256, 0, stream>>>(oidx, repmin, rep_of, n);

        long long nthr = (long long)n * NIN;
        mink_copy_reps<<<(int)(nthr / 256), 256, 0, stream>>>(
            feats, rep_of, buf, n);
        mink_dup_accum<<<(int)(nthr / 256), 256, 0, stream>>>(
            feats, rep_of, buf, n);

        mink_pack16<<<(n + 255) / 256, 256, 0, stream>>>(rep_of, buf, n);
        mink_invr<<<(num_out + 255) / 256, 256, 0, stream>>>(
            oidx, repmin, inv, num_out);

        int nwave = (num_out + 16 * TT - 1) / (16 * TT);
        mink_gather16<<<(nwave + 7) / 8, 512, 0, stream>>>(
            buf, wf, inv, bias, out, num_out);
    } else {
        // ---- fallback: round-4 atomic scatter
        mink_prep_w32<<<(KK * 4 * 64 + 255) / 256, 256, 0, stream>>>(weight, wf);
        mink_init_bias<<<(n4 + 255) / 256, 256, 0, stream>>>(
            (float4*)out, (const float4*)bias, n4);
        int ntiles = n / 32;
        mink_scatter_mfma<<<ntiles * 64 / 256, 256, 0, stream>>>(
            feats, wf, oidx, out, ntiles);
        mink_relu<<<(n4 + 255) / 256, 256, 0, stream>>>((float4*)out, n4);
    }
}

// Round 14
// 203.051 us; speedup vs baseline: 5.3571x; 1.0285x over previous
//
#include <hip/hip_runtime.h>

#define NIN 64
#define NOUT 32
#define KK 9
#define TT 4   // output tiles (of 16 rows) per wave in the gather

typedef __attribute__((ext_vector_type(8))) short bf16x8;
typedef __attribute__((ext_vector_type(4))) float f32x4;
typedef __attribute__((ext_vector_type(16))) float f32x16;
typedef __attribute__((ext_vector_type(8))) unsigned short u16x8;

// fp32 -> bf16 round-to-nearest-even
__device__ __forceinline__ unsigned short f2bf_rne(float f) {
    unsigned int u = __builtin_bit_cast(unsigned int, f);
    unsigned int r = (u + 0x7FFFu + ((u >> 16) & 1u)) >> 16;
    return (unsigned short)r;
}
__device__ __forceinline__ float bf2f(unsigned short h) {
    unsigned int u = ((unsigned int)h) << 16;
    return __builtin_bit_cast(float, u);
}

// ---------------------------------------------------------------------------
// Weights for the 16x16x32 gather: SINGLE bf16 (validated round 13: absmax
// unchanged at 0.03125). frag id fid = (k*2+kh)*2+ch; elem j of lane l:
//   ch_idx = kh*32 + 16*(j>>2) + (l>>4)*4 + (j&3),  col = ch*16 + (l&15)
__global__ void mink_prep_w16(const float* __restrict__ w,
                              unsigned short* __restrict__ wfB) {
    int t = blockIdx.x * 256 + threadIdx.x;
    if (t >= 36 * 64) return;
    int lane = t & 63, fid = t >> 6;
    int ch = fid & 1, kh = (fid >> 1) & 1, k = fid >> 2;
    int g = lane >> 4, col = ch * 16 + (lane & 15);
    #pragma unroll
    for (int j = 0; j < 8; ++j) {
        int ci = kh * 32 + 16 * (j >> 2) + g * 4 + (j & 3);
        wfB[(size_t)fid * 512 + lane * 8 + j] =
            f2bf_rne(w[(k * NIN + ci) * NOUT + col]);
    }
}

// ---------------------------------------------------------------------------
// Generic int fill.
__global__ void mink_fill(int4* __restrict__ p, long long n4, int v) {
    long long i = (long long)blockIdx.x * 256 + threadIdx.x;
    long long stride = (long long)gridDim.x * 256;
    int4 val = {v, v, v, v};
    for (; i < n4; i += stride) p[i] = val;
}

// ---------------------------------------------------------------------------
// Step 1: representative site per cell = min site id sharing the center row.
__global__ void mink_rep(const int* __restrict__ oidx, int* __restrict__ repmin,
                         int n) {
    int i = blockIdx.x * 256 + threadIdx.x;
    if (i < n) atomicMin(&repmin[oidx[(size_t)i * KK + 4]], i);
}

// ---------------------------------------------------------------------------
// Step 1b: materialize rep_of[site] once (round 13).
__global__ void mink_resolve(const int* __restrict__ oidx,
                             const int* __restrict__ repmin,
                             int* __restrict__ rep_of, int n) {
    int i = blockIdx.x * 256 + threadIdx.x;
    if (i < n) rep_of[i] = repmin[oidx[(size_t)i * KK + 4]];
}

// ---------------------------------------------------------------------------
// Step 2a: rep sites copy features into buf (plain stores, coalesced).
// MUST stay a separate launch from dup_accum (round-10 fusion raced).
__global__ void mink_copy_reps(const float* __restrict__ feats,
                               const int* __restrict__ rep_of,
                               float* __restrict__ buf, int n) {
    int t = blockIdx.x * 256 + threadIdx.x;
    int site = t >> 6;
    if (site >= n) return;
    if (rep_of[site] == site) buf[t] = feats[t];
}

// ---------------------------------------------------------------------------
// Step 2b: duplicates add into buf[rep]; wave-coalesced channels -> 4 line
// touches per dup site.
__global__ void mink_dup_accum(const float* __restrict__ feats,
                               const int* __restrict__ rep_of,
                               float* __restrict__ buf, int n) {
    int t = blockIdx.x * 256 + threadIdx.x;
    int site = t >> 6;
    if (site >= n) return;
    int rep = rep_of[site];
    if (rep != site)
        unsafeAtomicAdd(buf + (size_t)rep * NIN + (t & 63), feats[t]);
}

// ---------------------------------------------------------------------------
// Step 3: pack summed fp32 row -> single-bf16 A fragments, in place (128 B
// at the row start). chunk (kh,g) elem j: ch = kh*32 + 16*(j>>2) + g*4 + (j&3)
__global__ void mink_pack16(const int* __restrict__ rep_of,
                            float* __restrict__ buf, int n) {
    int i = blockIdx.x * 256 + threadIdx.x;
    if (i >= n) return;
    if (rep_of[i] != i) return;

    float x[NIN];
    float4* p4 = (float4*)(buf + (size_t)i * NIN);
    #pragma unroll
    for (int j = 0; j < NIN / 4; ++j) {
        float4 v = p4[j];
        x[j * 4 + 0] = v.x; x[j * 4 + 1] = v.y;
        x[j * 4 + 2] = v.z; x[j * 4 + 3] = v.w;
    }
    #pragma unroll
    for (int kh = 0; kh < 2; ++kh) {
        #pragma unroll
        for (int g = 0; g < 4; ++g) {
            u16x8 a;
            #pragma unroll
            for (int j = 0; j < 8; ++j) {
                int c = kh * 32 + 16 * (j >> 2) + g * 4 + (j & 3);
                a[j] = f2bf_rne(x[c]);
            }
            p4[kh * 4 + g] = __builtin_bit_cast(float4, a);
        }
    }
}

// ---------------------------------------------------------------------------
// Step 4: inverse maps in output-row order (round 12: near-monotonic writes).
__global__ void mink_invr(const int* __restrict__ oidx,
                          const int* __restrict__ repmin,
                          int* __restrict__ inv, int num_out) {
    int r = blockIdx.x * 256 + threadIdx.x;
    if (r >= num_out) return;
    int rep = repmin[r];
    if (rep == 0x7FFFFFFF) return;   // not a center row; planes pre-filled -1
    const int* ip = oidx + (size_t)rep * KK;
    #pragma unroll
    for (int k = 0; k < KK; ++k) {
        int row = (k == 4) ? r : ip[k];
        inv[(size_t)k * num_out + row] = rep;
    }
}

// ---------------------------------------------------------------------------
// Step 5: 16x16x32 gather, TT=4 tiles per wave, single-bf16 W read DIRECTLY
// from global (round 14: W is 36 KB == L1-resident; LDS staging was serial
// overhead + occupancy cap). 256-thread blocks -> 1856 blocks, no sync.
__global__ __launch_bounds__(256) void mink_gather16(
    const float* __restrict__ buf,          // packed bf16 A rows (128 B used)
    const unsigned short* __restrict__ wfB, // 36 frags x 1 KB (cache-resident)
    const int* __restrict__ inv,            // [9][num_out]
    const float* __restrict__ bias,         // [32]
    float* __restrict__ out,                // [num_out, 32]
    int num_out) {
    int wid  = (blockIdx.x * 256 + threadIdx.x) >> 6;
    int lane = threadIdx.x & 63;
    int r0   = wid * (16 * TT);
    if (r0 >= num_out) return;
    int g   = lane >> 4;
    int c16 = lane & 15;

    f32x4 acc[TT][2];
    #pragma unroll
    for (int t = 0; t < TT; ++t) {
        acc[t][0] = (f32x4){0, 0, 0, 0};
        acc[t][1] = (f32x4){0, 0, 0, 0};
    }

    #pragma unroll
    for (int k = 0; k < KK; ++k) {
        bf16x8 a0[TT], a1[TT];
        #pragma unroll
        for (int t = 0; t < TT; ++t) {
            int r = r0 + t * 16 + c16;
            int iv = (r < num_out) ? inv[(size_t)k * num_out + r] : -1;
            a0[t] = (bf16x8){0,0,0,0,0,0,0,0};
            a1[t] = (bf16x8){0,0,0,0,0,0,0,0};
            if (iv >= 0) {
                const bf16x8* ab = (const bf16x8*)(buf + (size_t)iv * NIN);
                a0[t] = ab[g];
                a1[t] = ab[4 + g];
            }
        }
        #pragma unroll
        for (int kh = 0; kh < 2; ++kh) {
            #pragma unroll
            for (int ch = 0; ch < 2; ++ch) {
                bf16x8 b = *(const bf16x8*)(
                    wfB + (size_t)((k * 2 + kh) * 2 + ch) * 512 + lane * 8);
                #pragma unroll
                for (int t = 0; t < TT; ++t) {
                    bf16x8 a = kh ? a1[t] : a0[t];
                    acc[t][ch] = __builtin_amdgcn_mfma_f32_16x16x32_bf16(
                        a, b, acc[t][ch], 0, 0, 0);
                }
            }
        }
    }

    // C/D: row = g*4 + reg, col = c16
    #pragma unroll
    for (int t = 0; t < TT; ++t) {
        #pragma unroll
        for (int ch = 0; ch < 2; ++ch) {
            float bb = bias[ch * 16 + c16];
            #pragma unroll
            for (int reg = 0; reg < 4; ++reg) {
                int orow = r0 + t * 16 + g * 4 + reg;
                if (orow < num_out)
                    out[(size_t)orow * NOUT + ch * 16 + c16] =
                        fmaxf(acc[t][ch][reg] + bb, 0.0f);
            }
        }
    }
}

// ---------------------------------------------------------------------------
// Fallback path (round-4 atomic scatter) if d_ws is too small.
__global__ void mink_prep_w32(const float* __restrict__ w,
                              unsigned short* __restrict__ wf) {
    int t = blockIdx.x * 256 + threadIdx.x;
    if (t >= KK * 4 * 64) return;
    int l = t & 63, ks = (t >> 6) & 3, k = t >> 8;
    int col = l & 31;
    int kb = ks * 16 + (l >> 5) * 4;
    #pragma unroll
    for (int j = 0; j < 8; ++j) {
        int c = kb + (j & 3) + 8 * (j >> 2);
        float v = w[(k * NIN + c) * NOUT + col];
        unsigned short hi = f2bf_rne(v);
        unsigned short lo = f2bf_rne(v - bf2f(hi));
        wf[(size_t)((k * 4 + ks) * 64 + l) * 8 + j] = hi;
        wf[(size_t)(KK * 4 * 64 * 8) + (size_t)((k * 4 + ks) * 64 + l) * 8 + j] = lo;
    }
}

__global__ void mink_init_bias(float4* __restrict__ out,
                               const float4* __restrict__ bias, int n4) {
    int i = blockIdx.x * blockDim.x + threadIdx.x;
    if (i < n4) out[i] = bias[i & 7];
}

__global__ __launch_bounds__(256) void mink_scatter_mfma(
    const float* __restrict__ feats,
    const unsigned short* __restrict__ wf,
    const int* __restrict__ out_idx,
    float* __restrict__ out,
    int ntiles) {
    int wid  = (blockIdx.x * 256 + threadIdx.x) >> 6;
    int lane = threadIdx.x & 63;
    if (wid >= ntiles) return;
    int n0   = wid * 32;
    int half = lane >> 5;
    int col  = lane & 31;

    const float* xrow = feats + (size_t)(n0 + col) * NIN;
    int kbase = half * 4;
    bf16x8 ahi[4], alo[4];
    #pragma unroll
    for (int ks = 0; ks < 4; ++ks) {
        float4 v0 = *(const float4*)(xrow + ks * 16 + kbase);
        float4 v1 = *(const float4*)(xrow + ks * 16 + kbase + 8);
        float xs[8] = {v0.x, v0.y, v0.z, v0.w, v1.x, v1.y, v1.z, v1.w};
        #pragma unroll
        for (int j = 0; j < 8; ++j) {
            unsigned short h = f2bf_rne(xs[j]);
            ahi[ks][j] = (short)h;
            alo[ks][j] = (short)f2bf_rne(xs[j] - bf2f(h));
        }
    }
    const bf16x8* wfh = (const bf16x8*)wf;
    const bf16x8* wfl = wfh + KK * 4 * 64;
    #pragma unroll 1
    for (int k = 0; k < KK; ++k) {
        f32x16 acc = {0,0,0,0,0,0,0,0,0,0,0,0,0,0,0,0};
        #pragma unroll
        for (int ks = 0; ks < 4; ++ks) {
            bf16x8 bh = wfh[(k * 4 + ks) * 64 + lane];
            bf16x8 bl = wfl[(k * 4 + ks) * 64 + lane];
            acc = __builtin_amdgcn_mfma_f32_32x32x16_bf16(ahi[ks], bh, acc, 0, 0, 0);
            acc = __builtin_amdgcn_mfma_f32_32x32x16_bf16(ahi[ks], bl, acc, 0, 0, 0);
            acc = __builtin_amdgcn_mfma_f32_32x32x16_bf16(alo[ks], bh, acc, 0, 0, 0);
        }
        #pragma unroll
        for (int rr = 0; rr < 16; ++rr) {
            int site = (rr & 3) + 8 * (rr >> 2) + 4 * half;
            int row = out_idx[(size_t)(n0 + site) * KK + k];
            unsafeAtomicAdd(out + (size_t)row * NOUT + col, acc[rr]);
        }
    }
}

__global__ void mink_relu(float4* __restrict__ out, int n4) {
    int i = blockIdx.x * blockDim.x + threadIdx.x;
    if (i < n4) {
        float4 v = out[i];
        v.x = fmaxf(v.x, 0.0f);
        v.y = fmaxf(v.y, 0.0f);
        v.z = fmaxf(v.z, 0.0f);
        v.w = fmaxf(v.w, 0.0f);
        out[i] = v;
    }
}

extern "C" void kernel_launch(void* const* d_in, const int* in_sizes, int n_in,
                              void* d_out, int out_size, void* d_ws, size_t ws_size,
                              hipStream_t stream) {
    const float* feats  = (const float*)d_in[0];  // [N, 64] f32
    const float* weight = (const float*)d_in[1];  // [9, 64, 32] f32
    const float* bias   = (const float*)d_in[2];  // [32] f32
    const int*   oidx   = (const int*)d_in[3];    // [N, 9] i32
    float* out = (float*)d_out;                   // [num_out, 32] f32

    int n       = in_sizes[0] / NIN;              // 262144
    int n4      = out_size / 4;
    int num_out = out_size / NOUT;

    // d_ws layout: wf(73728 reserved) | repmin | rep_of[n] | inv | buf
    unsigned short* wf = (unsigned short*)d_ws;
    size_t off = 73728;
    int* repmin = (int*)((char*)d_ws + off);  off += (size_t)num_out * 4 + 16;
    off = (off + 255) & ~(size_t)255;
    int* rep_of = (int*)((char*)d_ws + off);  off += (size_t)n * 4;
    off = (off + 255) & ~(size_t)255;
    int* inv    = (int*)((char*)d_ws + off);  off += (size_t)KK * num_out * 4 + 16;
    off = (off + 255) & ~(size_t)255;
    float* buf  = (float*)((char*)d_ws + off); off += (size_t)n * NIN * 4;

    if (off <= ws_size) {
        // ---- inverse-map 16x16 gather path (no output atomics)
        mink_prep_w16<<<(36 * 64 + 255) / 256, 256, 0, stream>>>(weight, wf);

        long long inv4c = ((long long)KK * num_out + 3) / 4;
        long long rep4c = ((long long)num_out + 3) / 4;
        mink_fill<<<1024, 256, 0, stream>>>((int4*)inv, inv4c, -1);
        mink_fill<<<256, 256, 0, stream>>>((int4*)repmin, rep4c, 0x7FFFFFFF);
        mink_rep<<<(n + 255) / 256, 256, 0, stream>>>(oidx, repmin, n);
        mink_resolve<<<(n + 255) / 256, 256, 0, stream>>>(oidx, repmin, rep_of, n);

        long long nthr = (long long)n * NIN;
        mink_copy_reps<<<(int)(nthr / 256), 256, 0, stream>>>(
            feats, rep_of, buf, n);
        mink_dup_accum<<<(int)(nthr / 256), 256, 0, stream>>>(
            feats, rep_of, buf, n);

        mink_pack16<<<(n + 255) / 256, 256, 0, stream>>>(rep_of, buf, n);
        mink_invr<<<(num_out + 255) / 256, 256, 0, stream>>>(
            oidx, repmin, inv, num_out);

        int nwave = (num_out + 16 * TT - 1) / (16 * TT);
        mink_gather16<<<(nwave + 3) / 4, 256, 0, stream>>>(
            buf, wf, inv, bias, out, num_out);
    } else {
        // ---- fallback: round-4 atomic scatter
        mink_prep_w32<<<(KK * 4 * 64 + 255) / 256, 256, 0, stream>>>(weight, wf);
        mink_init_bias<<<(n4 + 255) / 256, 256, 0, stream>>>(
            (float4*)out, (const float4*)bias, n4);
        int ntiles = n / 32;
        mink_scatter_mfma<<<ntiles * 64 / 256, 256, 0, stream>>>(
            feats, wf, oidx, out, ntiles);
        mink_relu<<<(n4 + 255) / 256, 256, 0, stream>>>((float4*)out, n4);
    }
}